// Round 2
// baseline (421.023 us; speedup 1.0000x reference)
//
#include <hip/hip_runtime.h>
#include <hip/hip_bf16.h>

typedef unsigned short u16;
typedef __attribute__((ext_vector_type(8))) short bf16x8;
typedef __attribute__((ext_vector_type(4))) float f32x4;

#define B_ 8
#define T_ 2048
#define BT_ (B_*T_)
#define DM_ 1024
#define DH_ 64
#define NCH_ 64            // chunks per batch
#define S_ (T_/NCH_)       // 32 steps per chunk
#define STATE_ 896         // leaf 256 + Ws 576 + z 64

__device__ __forceinline__ float b2f(u16 u){ unsigned v=((unsigned)u)<<16; float f; __builtin_memcpy(&f,&v,4); return f; }
__device__ __forceinline__ u16 f2b(float f){ __hip_bfloat16 h=__float2bfloat16(f); u16 u; __builtin_memcpy(&u,&h,2); return u; }

// dtype-flexible scalar load: f32 ? float : bf16
__device__ __forceinline__ float ldin(const void* p, size_t i, int f32){
  return f32 ? ((const float*)p)[i] : b2f(((const u16*)p)[i]);
}
// dtype-flexible 4-element load, returned as bf16 ushort4 (for MFMA staging)
__device__ __forceinline__ ushort4 ld4bf(const void* p, size_t i, int f32){
  if (f32){
    f32x4 v = *(const f32x4*)((const float*)p + i);
    ushort4 r; r.x=f2b(v[0]); r.y=f2b(v[1]); r.z=f2b(v[2]); r.w=f2b(v[3]); return r;
  }
  return *(const ushort4*)((const u16*)p + i);
}

// 88-vector layout: L0 n<8,r=4 @0 ; L1 n<4,r=8 @32 ; L2 n<2,r=8 @64 ; L3 n=1,r=8 @80
__device__ __forceinline__ void decode88(int f, int& l, int& n, int& ri){
  if (f<32){ l=0; n=f>>2; ri=f&3; }
  else if (f<64){ l=1; n=(f-32)>>3; ri=f&7; }
  else if (f<80){ l=2; n=(f-64)>>3; ri=f&7; }
  else { l=3; n=0; ri=f&7; }
}
// state[256..832) = Ws flat: L0@256(n*16+i*4+j), L1@384(n*64+i*8+j), L2@640, L3@768
__device__ __forceinline__ void decodeWs(int e, int& ia, int& ib){
  if (e<384){ int o=e-256, n=o>>4; ia=n*4+((o>>2)&3); ib=n*4+(o&3); }
  else if (e<640){ int o=e-384, n=o>>6; ia=32+n*8+((o>>3)&7); ib=32+n*8+(o&7); }
  else if (e<768){ int o=e-640, n=o>>6; ia=64+n*8+((o>>3)&7); ib=64+n*8+(o&7); }
  else { int o=e-768; ia=80+((o>>3)&7); ib=80+(o&7); }
}

// ---------------- Kernel 0: dtype detection ----------------
// Interpret first 4096 u16 of x as bf16: real-bf16 data ~100% sane exponents,
// fp32-data-read-as-u16 ~58% sane. flag=1 -> fp32.
__global__ __launch_bounds__(64) void k_detect(const u16* __restrict__ x, int* __restrict__ flag){
  int tid = threadIdx.x;
  int sane = 0;
  for (int i = tid; i < 4096; i += 64){
    u16 u = x[i];
    int e = (u >> 7) & 0xFF;
    if ((u & 0x7FFF) == 0 || (e >= 100 && e <= 140)) sane++;
  }
  #pragma unroll
  for (int o = 32; o > 0; o >>= 1) sane += __shfl_down(sane, o);
  if (tid == 0) flag[0] = (sane < 3600) ? 1 : 0;
}

// ---------------- Kernel 1: fused QKV projection (bf16 MFMA) ----------------
__global__ __launch_bounds__(256) void k_proj(
    const void* __restrict__ x, const void* __restrict__ Wq,
    const void* __restrict__ Wk, const void* __restrict__ Wv,
    float* __restrict__ oq, float* __restrict__ ok_, float* __restrict__ ov,
    const int* __restrict__ fl)
{
  __shared__ u16 As[64][72];
  __shared__ u16 Bs[64][72];
  const int f32 = fl[0];
  const int m = blockIdx.y;
  const void* __restrict__ W = (m==0)?Wq:((m==1)?Wk:Wv);
  float* __restrict__ outp = (m==0)?oq:((m==1)?ok_:ov);
  const int row0 = blockIdx.x*64;
  const int tid = threadIdx.x, lane = tid&63, w = tid>>6;
  const int quad = lane>>4, l16 = lane&15;
  const int c4 = tid&15, rb = tid>>4;
  f32x4 acc[4];
  #pragma unroll
  for (int nt=0;nt<4;nt++) acc[nt] = (f32x4){0.f,0.f,0.f,0.f};
  for (int k0=0;k0<DM_;k0+=64){
    #pragma unroll
    for (int p=0;p<4;p++){
      int r = rb + p*16;
      ushort4 xv = ld4bf(x, (size_t)(row0+r)*DM_ + k0 + c4*4, f32);
      *(ushort4*)&As[r][c4*4] = xv;
    }
    #pragma unroll
    for (int p=0;p<4;p++){
      int kr = rb + p*16;
      ushort4 wv4 = ld4bf(W, (size_t)(k0+kr)*DH_ + c4*4, f32);
      Bs[c4*4+0][kr]=wv4.x; Bs[c4*4+1][kr]=wv4.y; Bs[c4*4+2][kr]=wv4.z; Bs[c4*4+3][kr]=wv4.w;
    }
    __syncthreads();
    #pragma unroll
    for (int ks=0;ks<2;ks++){
      bf16x8 a = *(const bf16x8*)&As[w*16+l16][ks*32+quad*8];
      #pragma unroll
      for (int nt=0;nt<4;nt++){
        bf16x8 b = *(const bf16x8*)&Bs[nt*16+l16][ks*32+quad*8];
        acc[nt] = __builtin_amdgcn_mfma_f32_16x16x32_bf16(a,b,acc[nt],0,0,0);
      }
    }
    __syncthreads();
  }
  #pragma unroll
  for (int nt=0;nt<4;nt++)
    #pragma unroll
    for (int i=0;i<4;i++){
      int row = row0 + w*16 + quad*4 + i;
      int col = nt*16 + l16;
      float val = acc[nt][i];
      if (m<2) val = (val>0.f)? (val+1.f) : expf(val);  // elu1
      outp[(size_t)row*DH_ + col] = val;
    }
}

// ---------------- Kernel 2: per-token basis projections ----------------
__global__ __launch_bounds__(384) void k_prep(
    const float* __restrict__ gq, const float* __restrict__ gk, const float* __restrict__ gv,
    const void* __restrict__ UL0, const void* __restrict__ UL1, const void* __restrict__ UL2, const void* __restrict__ UL3,
    const void* __restrict__ VR0, const void* __restrict__ VR1, const void* __restrict__ VR2, const void* __restrict__ VR3,
    const void* __restrict__ VL0, const void* __restrict__ VL1, const void* __restrict__ VL2, const void* __restrict__ VL3,
    float* __restrict__ uLa, float* __restrict__ vRa, float* __restrict__ vrxa, float* __restrict__ vlxa,
    const int* __restrict__ fl)
{
  const int f32 = fl[0];
  const int row = blockIdx.x;
  int e = threadIdx.x;
  if (e>=352) return;
  int a=e/88, f=e-a*88;
  int l,n,ri; decode88(f,l,n,ri);
  const int BSl[4]={4,8,16,32}; const int Rl[4]={4,8,8,8};
  int bs=BSl[l], r=Rl[l];
  const float* src = (a==0)? (gk+(size_t)row*64) : (a==1)? (gv+(size_t)row*64) : (gq+(size_t)row*64);
  int off = n*2*bs + ((a==1||a==2)?bs:0);
  const void* U;
  if (a==0)      U = (l==0)?UL0:(l==1)?UL1:(l==2)?UL2:UL3;
  else if (a==3) U = (l==0)?VL0:(l==1)?VL1:(l==2)?VL2:VL3;
  else           U = (l==0)?VR0:(l==1)?VR1:(l==2)?VR2:VR3;
  float acc=0.f;
  for (int d=0; d<bs; d++) acc += src[off+d]*ldin(U, d*r+ri, f32);
  float* dst = (a==0)?uLa:(a==1)?vRa:(a==2)?vrxa:vlxa;
  dst[(size_t)row*88+f] = acc;
}

// ---------------- Kernel 3: per-chunk state sums ----------------
__global__ __launch_bounds__(256) void k_chunksum(
    const float* __restrict__ gk, const float* __restrict__ gv,
    const float* __restrict__ uLa, const float* __restrict__ vRa,
    float* __restrict__ SL)
{
  const int bid = blockIdx.x;
  const int b = bid/NCH_, c = bid%NCH_;
  const size_t base64 = (size_t)(b*T_ + c*S_)*64;
  const size_t base88 = (size_t)(b*T_ + c*S_)*88;
  for (int p=0;p<4;p++){
    int e = threadIdx.x + p*256;
    if (e>=STATE_) break;
    float acc=0.f;
    if (e < 256){
      int n=e>>4;
      const float* A = gk + base64 + n*4 + ((e>>2)&3);
      const float* Bp = gv + base64 + n*4 + (e&3);
      for (int s=0;s<S_;s++) acc += A[s*64]*Bp[s*64];
    } else if (e < 832){
      int ia, ib; decodeWs(e, ia, ib);
      const float* A = uLa + base88 + ia;
      const float* Bp = vRa + base88 + ib;
      for (int s=0;s<S_;s++) acc += A[s*88]*Bp[s*88];
    } else {
      const float* A = gk + base64 + (e-832);
      for (int s=0;s<S_;s++) acc += A[s*64];
    }
    SL[(size_t)bid*STATE_ + e] = acc;
  }
}

// ---------------- Kernel 4: exclusive prefix over chunks ----------------
__global__ __launch_bounds__(256) void k_prefix(const float* __restrict__ SL, float* __restrict__ SP){
  const int b = blockIdx.x;
  for (int p=0;p<4;p++){
    int e = threadIdx.x + p*256;
    if (e>=STATE_) break;
    float run=0.f;
    for (int c=0;c<NCH_;c++){
      size_t idx = ((size_t)(b*NCH_+c))*STATE_ + e;
      SP[idx] = run; run += SL[idx];
    }
  }
}

// ---------------- Kernel 5: sequential replay per chunk ----------------
__global__ __launch_bounds__(256) void k_scan(
    const float* __restrict__ gq, const float* __restrict__ gk, const float* __restrict__ gv,
    const float* __restrict__ uLa, const float* __restrict__ vRa,
    const float* __restrict__ vrxa, const float* __restrict__ vlxa,
    const float* __restrict__ SP,
    const void* __restrict__ UL0, const void* __restrict__ UL1, const void* __restrict__ UL2, const void* __restrict__ UL3,
    const void* __restrict__ UR0, const void* __restrict__ UR1, const void* __restrict__ UR2, const void* __restrict__ UR3,
    float* __restrict__ Y, const int* __restrict__ fl)
{
  __shared__ float st[STATE_];
  __shared__ float kb[64], vb[64], qb[64];
  __shared__ float uLb[88], vRb[88], vrxb[88], vlxb[88];
  __shared__ float gtop[88], gbot[88], yl[64], zqp[16];
  __shared__ float ULs[464], URs[464];   // level offsets {0,16,80,208}
  const int f32 = fl[0];
  const int tid = threadIdx.x;
  const int bid = blockIdx.x;
  const int b = bid/NCH_, c = bid%NCH_;
  for (int e=tid; e<STATE_; e+=256) st[e] = SP[(size_t)bid*STATE_+e];
  for (int e=tid; e<464; e+=256){
    int l, idx;
    if (e<16){ l=0; idx=e; } else if (e<80){ l=1; idx=e-16; }
    else if (e<208){ l=2; idx=e-80; } else { l=3; idx=e-208; }
    const void* ul = (l==0)?UL0:(l==1)?UL1:(l==2)?UL2:UL3;
    const void* ur = (l==0)?UR0:(l==1)?UR1:(l==2)?UR2:UR3;
    ULs[e] = ldin(ul, idx, f32); URs[e] = ldin(ur, idx, f32);
  }
  __syncthreads();
  const size_t row0 = (size_t)b*T_ + c*S_;
  for (int s=0; s<S_; s++){
    const size_t row = row0 + s;
    for (int e=tid; e<192; e+=256){
      if (e<64) kb[e] = gk[row*64+e];
      else if (e<128) vb[e-64] = gv[row*64+(e-64)];
      else qb[e-128] = gq[row*64+(e-128)];
    }
    for (int e=tid; e<352; e+=256){
      int a=e/88, f=e-a*88;
      const float* srcp = (a==0)?uLa:(a==1)?vRa:(a==2)?vrxa:vlxa;
      float val = srcp[row*88+f];
      float* dstp = (a==0)?uLb:(a==1)?vRb:(a==2)?vrxb:vlxb;
      dstp[f] = val;
    }
    __syncthreads();
    #pragma unroll
    for (int p=0;p<4;p++){
      int e = tid + p*256;
      if (e<STATE_){
        if (e<256){
          int n=e>>4;
          st[e] += kb[n*4+((e>>2)&3)]*vb[n*4+(e&3)];
        } else if (e<832){
          int ia, ib; decodeWs(e, ia, ib);
          st[e] += uLb[ia]*vRb[ib];
        } else {
          st[e] += kb[e-832];
        }
      }
    }
    __syncthreads();
    {
      const int Rl[4]={4,8,8,8};
      const int WSB[4]={256,384,640,768};
      const int O88[4]={0,32,64,80};
      int e = tid;
      if (e<88){
        int l,n,ri; decode88(e,l,n,ri);
        int r=Rl[l];
        int base = WSB[l] + n*r*r + ri*r;
        const float* vx = &vrxb[O88[l]+n*r];
        float acc=0.f;
        for (int j=0;j<r;j++) acc += st[base+j]*vx[j];     // Ws @ vr_x
        gtop[e]=acc;
      } else if (e<176){
        int f=e-88;
        int l,n,ri; decode88(f,l,n,ri);
        int r=Rl[l];
        int base = WSB[l] + n*r*r + ri;
        const float* vx = &vlxb[O88[l]+n*r];
        float acc=0.f;
        for (int j=0;j<r;j++) acc += st[base+j*r]*vx[j];   // Ws^T @ vl_x
        gbot[f]=acc;
      } else if (e<240){
        int jj=e-176; int n=jj>>2, i=jj&3;
        float acc=0.f;
        #pragma unroll
        for (int j=0;j<4;j++) acc += st[n*16+i*4+j]*qb[n*4+j];
        yl[jj]=acc;
      } else if (e<256){
        int pp=e-240; float acc=0.f;
        #pragma unroll
        for (int d=0;d<4;d++) acc += st[832+pp*4+d]*qb[pp*4+d];
        zqp[pp]=acc;
      }
    }
    __syncthreads();
    if (tid<64){
      const int BSl[4]={4,8,16,32};
      const int Rl[4]={4,8,8,8};
      const int O88[4]={0,32,64,80};
      const int UOFF[4]={0,16,80,208};
      const int SH[4]={3,4,5,6};
      int j = tid;
      float y = yl[j];
      #pragma unroll
      for (int l=0;l<4;l++){
        int bs=BSl[l], r=Rl[l];
        int seg = j >> SH[l];
        int pos = j & (2*bs-1);
        if (pos < bs){
          const float* g = &gtop[O88[l]+seg*r];
          const float* u = &ULs[UOFF[l]+pos*r];
          for (int i=0;i<r;i++) y += u[i]*g[i];
        } else {
          const float* g = &gbot[O88[l]+seg*r];
          const float* u = &URs[UOFF[l]+(pos-bs)*r];
          for (int i=0;i<r;i++) y += u[i]*g[i];
        }
      }
      float dn=0.f;
      #pragma unroll
      for (int p2=0;p2<16;p2++) dn += zqp[p2];
      dn = fmaxf(dn, 1e-6f);
      Y[row*64 + j] = y/dn;
    }
    __syncthreads();
  }
}

// ---------------- Kernel 6: output projection Y @ Wo (bf16 MFMA) ----------------
__global__ __launch_bounds__(256) void k_outproj(
    const float* __restrict__ Y, const void* __restrict__ Wo, void* __restrict__ outv,
    const int* __restrict__ fl)
{
  __shared__ u16 As[64][72];
  __shared__ u16 Bs[64][72];
  const int f32 = fl[0];
  const int row0 = blockIdx.x*64, n0 = blockIdx.y*64;
  const int tid = threadIdx.x, lane = tid&63, w = tid>>6;
  const int quad = lane>>4, l16 = lane&15;
  const int c4 = tid&15, rb = tid>>4;
  #pragma unroll
  for (int p=0;p<4;p++){
    int r = rb+p*16;
    f32x4 f4 = *(const f32x4*)(Y + (size_t)(row0+r)*64 + c4*4);
    ushort4 u4; u4.x=f2b(f4[0]); u4.y=f2b(f4[1]); u4.z=f2b(f4[2]); u4.w=f2b(f4[3]);
    *(ushort4*)&As[r][c4*4] = u4;
  }
  #pragma unroll
  for (int p=0;p<4;p++){
    int kr = rb+p*16;
    ushort4 wv4 = ld4bf(Wo, (size_t)kr*DM_ + n0 + c4*4, f32);
    Bs[c4*4+0][kr]=wv4.x; Bs[c4*4+1][kr]=wv4.y; Bs[c4*4+2][kr]=wv4.z; Bs[c4*4+3][kr]=wv4.w;
  }
  __syncthreads();
  f32x4 acc[4];
  #pragma unroll
  for (int nt=0;nt<4;nt++) acc[nt] = (f32x4){0.f,0.f,0.f,0.f};
  #pragma unroll
  for (int ks=0;ks<2;ks++){
    bf16x8 a = *(const bf16x8*)&As[w*16+l16][ks*32+quad*8];
    #pragma unroll
    for (int nt=0;nt<4;nt++){
      bf16x8 b = *(const bf16x8*)&Bs[nt*16+l16][ks*32+quad*8];
      acc[nt] = __builtin_amdgcn_mfma_f32_16x16x32_bf16(a,b,acc[nt],0,0,0);
    }
  }
  #pragma unroll
  for (int nt=0;nt<4;nt++)
    #pragma unroll
    for (int i=0;i<4;i++){
      int row = row0 + w*16 + quad*4 + i;
      int col = n0 + nt*16 + l16;
      size_t idx = (size_t)row*DM_ + col;
      if (f32) ((float*)outv)[idx] = acc[nt][i];
      else ((u16*)outv)[idx] = f2b(acc[nt][i]);
    }
}

extern "C" void kernel_launch(void* const* d_in, const int* in_sizes, int n_in,
                              void* d_out, int out_size, void* d_ws, size_t ws_size,
                              hipStream_t stream) {
  const void* x  = d_in[0];
  const void* Wq = d_in[1];
  const void* Wk = d_in[2];
  const void* Wv = d_in[3];
  const void* Wo = d_in[4];
  const void* UL[4] = {d_in[5],d_in[6],d_in[7],d_in[8]};
  const void* VR[4] = {d_in[9],d_in[10],d_in[11],d_in[12]};
  const void* UR[4] = {d_in[13],d_in[14],d_in[15],d_in[16]};
  const void* VL[4] = {d_in[17],d_in[18],d_in[19],d_in[20]};

  int* flag = (int*)d_ws;
  float* ws = (float*)d_ws + 16;   // keep 64B offset, 16B alignment
  float* q    = ws;
  float* kf   = q    + (size_t)BT_*64;
  float* vf   = kf   + (size_t)BT_*64;
  float* uLa  = vf   + (size_t)BT_*64;
  float* vRa  = uLa  + (size_t)BT_*88;
  float* vrxa = vRa  + (size_t)BT_*88;
  float* vlxa = vrxa + (size_t)BT_*88;
  float* SL   = vlxa + (size_t)BT_*88;
  float* SP   = SL   + (size_t)B_*NCH_*STATE_;
  float* Y    = SP   + (size_t)B_*NCH_*STATE_;

  k_detect<<<1, 64, 0, stream>>>((const u16*)x, flag);
  k_proj<<<dim3(BT_/64,3), 256, 0, stream>>>(x, Wq, Wk, Wv, q, kf, vf, flag);
  k_prep<<<BT_, 384, 0, stream>>>(q, kf, vf,
      UL[0],UL[1],UL[2],UL[3], VR[0],VR[1],VR[2],VR[3], VL[0],VL[1],VL[2],VL[3],
      uLa, vRa, vrxa, vlxa, flag);
  k_chunksum<<<B_*NCH_, 256, 0, stream>>>(kf, vf, uLa, vRa, SL);
  k_prefix<<<B_, 256, 0, stream>>>(SL, SP);
  k_scan<<<B_*NCH_, 256, 0, stream>>>(q, kf, vf, uLa, vRa, vrxa, vlxa, SP,
      UL[0],UL[1],UL[2],UL[3], UR[0],UR[1],UR[2],UR[3], Y, flag);
  k_outproj<<<dim3(BT_/64, DM_/64), 256, 0, stream>>>(Y, Wo, d_out, flag);
}

// Round 4
// 402.070 us; speedup vs baseline: 1.0471x; 1.0471x over previous
//
#include <hip/hip_runtime.h>
#include <hip/hip_bf16.h>

typedef unsigned short u16;
typedef __attribute__((ext_vector_type(8))) short bf16x8;
typedef __attribute__((ext_vector_type(4))) float f32x4;

#define B_ 8
#define T_ 2048
#define BT_ (B_*T_)
#define DM_ 1024
#define DH_ 64
#define NCH_ 64            // chunks per batch
#define S_ (T_/NCH_)       // 32 steps per chunk
#define STATE_ 896         // leaf 256 + Ws 576 + z 64

__device__ __forceinline__ float b2f(u16 u){ unsigned v=((unsigned)u)<<16; float f; __builtin_memcpy(&f,&v,4); return f; }
__device__ __forceinline__ u16 f2b(float f){ __hip_bfloat16 h=__float2bfloat16(f); u16 u; __builtin_memcpy(&u,&h,2); return u; }

__device__ __forceinline__ float ldin(const void* p, size_t i, int f32){
  return f32 ? ((const float*)p)[i] : b2f(((const u16*)p)[i]);
}
__device__ __forceinline__ ushort4 ld4bf(const void* p, size_t i, int f32){
  if (f32){
    f32x4 v = *(const f32x4*)((const float*)p + i);
    ushort4 r; r.x=f2b(v[0]); r.y=f2b(v[1]); r.z=f2b(v[2]); r.w=f2b(v[3]); return r;
  }
  return *(const ushort4*)((const u16*)p + i);
}

// state layout: leaf [0,256): n*16+i*4+j ; Ws: L0@256 (n*16+i*4+j), L1@384 (n*64+i*8+j),
// L2@640, L3@768 ; z@832..896
__device__ __forceinline__ void decodeWs(int e, int& ia, int& ib){
  if (e<384){ int o=e-256, n=o>>4; ia=n*4+((o>>2)&3); ib=n*4+(o&3); }
  else if (e<640){ int o=e-384, n=o>>6; ia=32+n*8+((o>>3)&7); ib=32+n*8+(o&7); }
  else if (e<768){ int o=e-640, n=o>>6; ia=64+n*8+((o>>3)&7); ib=64+n*8+(o&7); }
  else { int o=e-768; ia=80+((o>>3)&7); ib=80+(o&7); }
}
__device__ __forceinline__ void decode88(int f, int& l, int& n, int& ri){
  if (f<32){ l=0; n=f>>2; ri=f&3; }
  else if (f<64){ l=1; n=(f-32)>>3; ri=f&7; }
  else if (f<80){ l=2; n=(f-64)>>3; ri=f&7; }
  else { l=3; n=0; ri=f&7; }
}

// ---------------- Kernel 0: dtype detection ----------------
__global__ __launch_bounds__(64) void k_detect(const u16* __restrict__ x, int* __restrict__ flag){
  int tid = threadIdx.x;
  int sane = 0;
  for (int i = tid; i < 4096; i += 64){
    u16 u = x[i];
    int e = (u >> 7) & 0xFF;
    if ((u & 0x7FFF) == 0 || (e >= 100 && e <= 140)) sane++;
  }
  #pragma unroll
  for (int o = 32; o > 0; o >>= 1) sane += __shfl_down(sane, o);
  if (tid == 0) flag[0] = (sane < 3600) ? 1 : 0;
}

// ---------------- Kernel 1: fused QKV projection (one x pass, N=192) ----------------
__global__ __launch_bounds__(256) void k_proj(
    const void* __restrict__ x, const void* __restrict__ Wq,
    const void* __restrict__ Wk, const void* __restrict__ Wv,
    float* __restrict__ oq, float* __restrict__ ok_, float* __restrict__ ov,
    const int* __restrict__ fl)
{
  __shared__ u16 As[64][72];
  __shared__ u16 Bs[192][72];
  const int f32 = fl[0];
  const int row0 = blockIdx.x*64;
  const int tid = threadIdx.x, lane = tid&63, w = tid>>6;
  const int quad = lane>>4, l16 = lane&15;
  const int c4 = tid&15, rb = tid>>4;
  f32x4 acc[12];
  #pragma unroll
  for (int nt=0;nt<12;nt++) acc[nt] = (f32x4){0.f,0.f,0.f,0.f};
  for (int k0=0;k0<DM_;k0+=64){
    #pragma unroll
    for (int p=0;p<4;p++){
      int r = rb + p*16;
      ushort4 xv = ld4bf(x, (size_t)(row0+r)*DM_ + k0 + c4*4, f32);
      *(ushort4*)&As[r][c4*4] = xv;
    }
    #pragma unroll
    for (int m=0;m<3;m++){
      const void* W = (m==0)?Wq:((m==1)?Wk:Wv);
      #pragma unroll
      for (int p=0;p<4;p++){
        int kr = rb + p*16;
        ushort4 wv4 = ld4bf(W, (size_t)(k0+kr)*DH_ + c4*4, f32);
        Bs[m*64+c4*4+0][kr]=wv4.x; Bs[m*64+c4*4+1][kr]=wv4.y;
        Bs[m*64+c4*4+2][kr]=wv4.z; Bs[m*64+c4*4+3][kr]=wv4.w;
      }
    }
    __syncthreads();
    #pragma unroll
    for (int ks=0;ks<2;ks++){
      bf16x8 a = *(const bf16x8*)&As[w*16+l16][ks*32+quad*8];
      #pragma unroll
      for (int nt=0;nt<12;nt++){
        bf16x8 b = *(const bf16x8*)&Bs[nt*16+l16][ks*32+quad*8];
        acc[nt] = __builtin_amdgcn_mfma_f32_16x16x32_bf16(a,b,acc[nt],0,0,0);
      }
    }
    __syncthreads();
  }
  #pragma unroll
  for (int nt=0;nt<12;nt++){
    int m = nt>>2;
    float* __restrict__ outp = (m==0)?oq:((m==1)?ok_:ov);
    #pragma unroll
    for (int i=0;i<4;i++){
      int row = row0 + w*16 + quad*4 + i;
      int col = (nt&3)*16 + l16;
      float val = acc[nt][i];
      if (m<2) val = (val>0.f)? (val+1.f) : expf(val);  // elu1
      outp[(size_t)row*DH_ + col] = val;
    }
  }
}

// ---------------- Kernel 2: per-token basis projections ----------------
__global__ __launch_bounds__(384) void k_prep(
    const float* __restrict__ gq, const float* __restrict__ gk, const float* __restrict__ gv,
    const void* __restrict__ UL0, const void* __restrict__ UL1, const void* __restrict__ UL2, const void* __restrict__ UL3,
    const void* __restrict__ VR0, const void* __restrict__ VR1, const void* __restrict__ VR2, const void* __restrict__ VR3,
    const void* __restrict__ VL0, const void* __restrict__ VL1, const void* __restrict__ VL2, const void* __restrict__ VL3,
    float* __restrict__ uLa, float* __restrict__ vRa, float* __restrict__ vrxa, float* __restrict__ vlxa,
    const int* __restrict__ fl)
{
  const int f32 = fl[0];
  const int row = blockIdx.x;
  int e = threadIdx.x;
  if (e>=352) return;
  int a=e/88, f=e-a*88;
  int l,n,ri; decode88(f,l,n,ri);
  const int BSl[4]={4,8,16,32}; const int Rl[4]={4,8,8,8};
  int bs=BSl[l], r=Rl[l];
  const float* src = (a==0)? (gk+(size_t)row*64) : (a==1)? (gv+(size_t)row*64) : (gq+(size_t)row*64);
  int off = n*2*bs + ((a==1||a==2)?bs:0);
  const void* U;
  if (a==0)      U = (l==0)?UL0:(l==1)?UL1:(l==2)?UL2:UL3;
  else if (a==3) U = (l==0)?VL0:(l==1)?VL1:(l==2)?VL2:VL3;
  else           U = (l==0)?VR0:(l==1)?VR1:(l==2)?VR2:VR3;
  float acc=0.f;
  for (int d=0; d<bs; d++) acc += src[off+d]*ldin(U, d*r+ri, f32);
  float* dst = (a==0)?uLa:(a==1)?vRa:(a==2)?vrxa:vlxa;
  dst[(size_t)row*88+f] = acc;
}

// ---------------- Kernel 3: per-chunk state sums ----------------
__global__ __launch_bounds__(256) void k_chunksum(
    const float* __restrict__ gk, const float* __restrict__ gv,
    const float* __restrict__ uLa, const float* __restrict__ vRa,
    float* __restrict__ SL)
{
  const int bid = blockIdx.x;
  const int b = bid/NCH_, c = bid%NCH_;
  const size_t base64 = (size_t)(b*T_ + c*S_)*64;
  const size_t base88 = (size_t)(b*T_ + c*S_)*88;
  for (int p=0;p<4;p++){
    int e = threadIdx.x + p*256;
    if (e>=STATE_) break;
    float acc=0.f;
    if (e < 256){
      int n=e>>4;
      const float* A = gk + base64 + n*4 + ((e>>2)&3);
      const float* Bp = gv + base64 + n*4 + (e&3);
      for (int s=0;s<S_;s++) acc += A[s*64]*Bp[s*64];
    } else if (e < 832){
      int ia, ib; decodeWs(e, ia, ib);
      const float* A = uLa + base88 + ia;
      const float* Bp = vRa + base88 + ib;
      for (int s=0;s<S_;s++) acc += A[s*88]*Bp[s*88];
    } else {
      const float* A = gk + base64 + (e-832);
      for (int s=0;s<S_;s++) acc += A[s*64];
    }
    SL[(size_t)bid*STATE_ + e] = acc;
  }
}

// ---------------- Kernel 4: exclusive prefix over chunks ----------------
__global__ __launch_bounds__(256) void k_prefix(const float* __restrict__ SL, float* __restrict__ SP){
  const int b = blockIdx.x;
  for (int p=0;p<4;p++){
    int e = threadIdx.x + p*256;
    if (e>=STATE_) break;
    float run=0.f;
    for (int c=0;c<NCH_;c++){
      size_t idx = ((size_t)(b*NCH_+c))*STATE_ + e;
      SP[idx] = run; run += SL[idx];
    }
  }
}

// ---------------- Kernel 5: parallel intra-chunk (replaces sequential scan) ----
// y_t = S0-part + sum_{s<=t} rank1-parts. 8 lanes per token, wave w owns tokens
// 8w..8w+7 (wave-uniform s bound). No barriers in the hot s-loop.
__global__ __launch_bounds__(256) void k_intra(
    const float* __restrict__ gq, const float* __restrict__ gk, const float* __restrict__ gv,
    const float* __restrict__ uLa, const float* __restrict__ vRa,
    const float* __restrict__ vrxa, const float* __restrict__ vlxa,
    const float* __restrict__ SP,
    const void* __restrict__ UL0, const void* __restrict__ UL1, const void* __restrict__ UL2, const void* __restrict__ UL3,
    const void* __restrict__ UR0, const void* __restrict__ UR1, const void* __restrict__ UR2, const void* __restrict__ UR3,
    float* __restrict__ Y, const int* __restrict__ fl)
{
  __shared__ float kS[S_*64];        // 8 KB
  __shared__ float vS[S_*64];        // 8 KB
  __shared__ float uvS[S_*176];      // uL at [s][0..88), vR at [s][88..176); reused as gtop/gbot
  __shared__ float st0[STATE_];
  __shared__ float ULs[464], URs[464];
  const int f32 = fl[0];
  const int tid = threadIdx.x;
  const int bid = blockIdx.x;
  const int b = bid/NCH_, c = bid%NCH_;
  const int row0 = b*T_ + c*S_;

  // ---- stage chunk data (coalesced) ----
  const size_t r64 = (size_t)row0*64;
  for (int i=tid;i<S_*64;i+=256){ kS[i]=gk[r64+i]; vS[i]=gv[r64+i]; }
  const size_t r88 = (size_t)row0*88;
  for (int i=tid;i<S_*88;i+=256){
    int s=i/88, f=i-s*88;
    uvS[s*176+f]    = uLa[r88+i];
    uvS[s*176+88+f] = vRa[r88+i];
  }
  for (int e=tid;e<STATE_;e+=256) st0[e] = SP[(size_t)bid*STATE_+e];
  for (int e=tid;e<464;e+=256){
    int l, idx;
    if (e<16){ l=0; idx=e; } else if (e<80){ l=1; idx=e-16; }
    else if (e<208){ l=2; idx=e-80; } else { l=3; idx=e-208; }
    const void* ul = (l==0)?UL0:(l==1)?UL1:(l==2)?UL2:UL3;
    const void* ur = (l==0)?UR0:(l==1)?UR1:(l==2)?UR2:UR3;
    ULs[e] = ldin(ul, idx, f32); URs[e] = ldin(ur, idx, f32);
  }
  __syncthreads();

  const int w = tid>>6, lane = tid&63, tl = lane>>3, g = lane&7;
  const int t = w*8 + tl;
  const int n1 = g>>1, ri1 = (g&1)*4;
  const int n2 = g>>2, ri2 = (g&3)*2;
  const size_t row = (size_t)(row0 + t);

  // ---- per-token register data ----
  float qr[8];
  { const float* qp = gq + row*64 + g*8;
    *(f32x4*)&qr[0] = *(const f32x4*)qp; *(f32x4*)&qr[4] = *(const f32x4*)(qp+4); }
  float rxL0[4], lxL0[4], rxL1[8], lxL1[8], rxL2[8], lxL2[8], rxL3[8], lxL3[8];
  { const float* rp = vrxa + row*88; const float* lp = vlxa + row*88;
    *(f32x4*)&rxL0[0] = *(const f32x4*)(rp + 4*g);
    *(f32x4*)&lxL0[0] = *(const f32x4*)(lp + 4*g);
    *(f32x4*)&rxL1[0] = *(const f32x4*)(rp + 32 + n1*8); *(f32x4*)&rxL1[4] = *(const f32x4*)(rp + 36 + n1*8);
    *(f32x4*)&lxL1[0] = *(const f32x4*)(lp + 32 + n1*8); *(f32x4*)&lxL1[4] = *(const f32x4*)(lp + 36 + n1*8);
    *(f32x4*)&rxL2[0] = *(const f32x4*)(rp + 64 + n2*8); *(f32x4*)&rxL2[4] = *(const f32x4*)(rp + 68 + n2*8);
    *(f32x4*)&lxL2[0] = *(const f32x4*)(lp + 64 + n2*8); *(f32x4*)&lxL2[4] = *(const f32x4*)(lp + 68 + n2*8);
    *(f32x4*)&rxL3[0] = *(const f32x4*)(rp + 80); *(f32x4*)&rxL3[4] = *(const f32x4*)(rp + 84);
    *(f32x4*)&lxL3[0] = *(const f32x4*)(lp + 80); *(f32x4*)&lxL3[4] = *(const f32x4*)(lp + 84); }

  // ---- init from chunk-entry state S0 ----
  float yacc[8], den = 0.f;
  #pragma unroll
  for (int cc=0;cc<8;cc++){
    int n = 2*g + (cc>>2);
    const float* m = &st0[n*16 + (cc&3)*4];
    const float* qp = &qr[(cc>>2)*4];
    yacc[cc] = m[0]*qp[0]+m[1]*qp[1]+m[2]*qp[2]+m[3]*qp[3];
    den += st0[832 + g*8 + cc]*qr[cc];
  }
  float gtL0[4], gbL0[4], gtL1[4], gbL1[4], gtL2[2], gbL2[2], gtL3, gbL3;
  #pragma unroll
  for (int cc=0;cc<4;cc++){
    const float* m = &st0[256 + g*16 + cc*4];
    gtL0[cc] = m[0]*rxL0[0]+m[1]*rxL0[1]+m[2]*rxL0[2]+m[3]*rxL0[3];
    float s2 = 0.f;
    #pragma unroll
    for (int j=0;j<4;j++) s2 += st0[256 + g*16 + j*4 + cc]*lxL0[j];
    gbL0[cc] = s2;
  }
  #pragma unroll
  for (int cc=0;cc<4;cc++){
    int ri = ri1 + cc;
    float s1=0.f, s2=0.f;
    #pragma unroll
    for (int j=0;j<8;j++){
      s1 += st0[384 + n1*64 + ri*8 + j]*rxL1[j];
      s2 += st0[384 + n1*64 + j*8 + ri]*lxL1[j];
    }
    gtL1[cc]=s1; gbL1[cc]=s2;
  }
  #pragma unroll
  for (int cc=0;cc<2;cc++){
    int ri = ri2 + cc;
    float s1=0.f, s2=0.f;
    #pragma unroll
    for (int j=0;j<8;j++){
      s1 += st0[640 + n2*64 + ri*8 + j]*rxL2[j];
      s2 += st0[640 + n2*64 + j*8 + ri]*lxL2[j];
    }
    gtL2[cc]=s1; gbL2[cc]=s2;
  }
  { float s1=0.f, s2=0.f;
    #pragma unroll
    for (int j=0;j<8;j++){
      s1 += st0[768 + g*8 + j]*rxL3[j];
      s2 += st0[768 + j*8 + g]*lxL3[j];
    }
    gtL3=s1; gbL3=s2; }

  // ---- hot loop over s (no barriers) ----
  const int smax = w*8 + 8;
  for (int s=0; s<smax; s++){
    const float* ks_ = &kS[s*64 + g*8];
    const float* vs_ = &vS[s*64 + g*8];
    const float* uL_ = &uvS[s*176];
    const float* vR_ = &uvS[s*176 + 88];
    float dv0 = vs_[0]*qr[0]+vs_[1]*qr[1]+vs_[2]*qr[2]+vs_[3]*qr[3];
    float dv1 = vs_[4]*qr[4]+vs_[5]*qr[5]+vs_[6]*qr[6]+vs_[7]*qr[7];
    float dn = 0.f;
    #pragma unroll
    for (int cc=0;cc<8;cc++) dn += ks_[cc]*qr[cc];
    float d1L0=0.f,d2L0=0.f;
    #pragma unroll
    for (int j=0;j<4;j++){ d1L0 += vR_[4*g+j]*rxL0[j]; d2L0 += uL_[4*g+j]*lxL0[j]; }
    float d1L1=0.f,d2L1=0.f;
    #pragma unroll
    for (int j=0;j<8;j++){ d1L1 += vR_[32+n1*8+j]*rxL1[j]; d2L1 += uL_[32+n1*8+j]*lxL1[j]; }
    float d1L2=0.f,d2L2=0.f;
    #pragma unroll
    for (int j=0;j<8;j++){ d1L2 += vR_[64+n2*8+j]*rxL2[j]; d2L2 += uL_[64+n2*8+j]*lxL2[j]; }
    float d1L3=0.f,d2L3=0.f;
    #pragma unroll
    for (int j=0;j<8;j++){ d1L3 += vR_[80+j]*rxL3[j]; d2L3 += uL_[80+j]*lxL3[j]; }
    if (s<=t){
      den += dn;
      #pragma unroll
      for (int cc=0;cc<8;cc++) yacc[cc] += ks_[cc]*((cc<4)?dv0:dv1);
      #pragma unroll
      for (int cc=0;cc<4;cc++){
        gtL0[cc] += uL_[4*g+cc]*d1L0;          gbL0[cc] += vR_[4*g+cc]*d2L0;
        gtL1[cc] += uL_[32+n1*8+ri1+cc]*d1L1;  gbL1[cc] += vR_[32+n1*8+ri1+cc]*d2L1;
      }
      #pragma unroll
      for (int cc=0;cc<2;cc++){
        gtL2[cc] += uL_[64+n2*8+ri2+cc]*d1L2;  gbL2[cc] += vR_[64+n2*8+ri2+cc]*d2L2;
      }
      gtL3 += uL_[80+g]*d1L3;  gbL3 += vR_[80+g]*d2L3;
    }
  }
  __syncthreads();   // all waves done reading uvS — safe to overwrite as gtop/gbot

  // ---- write gtop/gbot, then combine with UL/UR ----
  { float* gr = &uvS[t*176];
    #pragma unroll
    for (int cc=0;cc<4;cc++){
      gr[4*g+cc] = gtL0[cc];                 gr[88+4*g+cc] = gbL0[cc];
      gr[32+n1*8+ri1+cc] = gtL1[cc];         gr[88+32+n1*8+ri1+cc] = gbL1[cc];
    }
    #pragma unroll
    for (int cc=0;cc<2;cc++){
      gr[64+n2*8+ri2+cc] = gtL2[cc];         gr[88+64+n2*8+ri2+cc] = gbL2[cc];
    }
    gr[80+g] = gtL3;  gr[88+80+g] = gbL3;
  }
  __syncthreads();

  den += __shfl_xor(den,1); den += __shfl_xor(den,2); den += __shfl_xor(den,4);
  float inv = 1.f / fmaxf(den, 1e-6f);
  const float* gr = &uvS[t*176];
  float yout[8];
  #pragma unroll
  for (int cc=0;cc<8;cc++){
    int j = g*8 + cc;
    float y = yacc[cc];
    // L0: bs=4, seg=j>>3=g, pos=j&7=cc
    if (cc<4){
      #pragma unroll
      for (int rr=0;rr<4;rr++) y += ULs[cc*4+rr]*gr[g*4+rr];
    } else {
      #pragma unroll
      for (int rr=0;rr<4;rr++) y += URs[(cc-4)*4+rr]*gr[88+g*4+rr];
    }
    // L1: bs=8
    { int seg=j>>4, pos=j&15;
      if (pos<8){
        #pragma unroll
        for (int rr=0;rr<8;rr++) y += ULs[16+pos*8+rr]*gr[32+seg*8+rr];
      } else {
        #pragma unroll
        for (int rr=0;rr<8;rr++) y += URs[16+(pos-8)*8+rr]*gr[88+32+seg*8+rr];
      } }
    // L2: bs=16
    { int seg=j>>5, pos=j&31;
      if (pos<16){
        #pragma unroll
        for (int rr=0;rr<8;rr++) y += ULs[80+pos*8+rr]*gr[64+seg*8+rr];
      } else {
        #pragma unroll
        for (int rr=0;rr<8;rr++) y += URs[80+(pos-16)*8+rr]*gr[88+64+seg*8+rr];
      } }
    // L3: bs=32
    { int pos=j;
      if (pos<32){
        #pragma unroll
        for (int rr=0;rr<8;rr++) y += ULs[208+pos*8+rr]*gr[80+rr];
      } else {
        #pragma unroll
        for (int rr=0;rr<8;rr++) y += URs[208+(pos-32)*8+rr]*gr[88+80+rr];
      } }
    yout[cc] = y*inv;
  }
  float* yp = Y + row*64 + g*8;
  *(f32x4*)yp = *(f32x4*)&yout[0];
  *(f32x4*)(yp+4) = *(f32x4*)&yout[4];
}

// ---------------- Kernel 6: output projection Y @ Wo (bf16 MFMA) ----------------
__global__ __launch_bounds__(256) void k_outproj(
    const float* __restrict__ Y, const void* __restrict__ Wo, void* __restrict__ outv,
    const int* __restrict__ fl)
{
  __shared__ u16 As[64][72];
  __shared__ u16 Bs[64][72];
  const int f32 = fl[0];
  const int row0 = blockIdx.x*64, n0 = blockIdx.y*64;
  const int tid = threadIdx.x, lane = tid&63, w = tid>>6;
  const int quad = lane>>4, l16 = lane&15;
  const int c4 = tid&15, rb = tid>>4;
  #pragma unroll
  for (int p=0;p<4;p++){
    int r = rb+p*16;
    f32x4 f4 = *(const f32x4*)(Y + (size_t)(row0+r)*64 + c4*4);
    ushort4 u4; u4.x=f2b(f4[0]); u4.y=f2b(f4[1]); u4.z=f2b(f4[2]); u4.w=f2b(f4[3]);
    *(ushort4*)&As[r][c4*4] = u4;
  }
  #pragma unroll
  for (int p=0;p<4;p++){
    int kr = rb+p*16;
    ushort4 wv4 = ld4bf(Wo, (size_t)kr*DM_ + n0 + c4*4, f32);
    Bs[c4*4+0][kr]=wv4.x; Bs[c4*4+1][kr]=wv4.y; Bs[c4*4+2][kr]=wv4.z; Bs[c4*4+3][kr]=wv4.w;
  }
  __syncthreads();
  f32x4 acc[4];
  #pragma unroll
  for (int nt=0;nt<4;nt++) acc[nt] = (f32x4){0.f,0.f,0.f,0.f};
  #pragma unroll
  for (int ks=0;ks<2;ks++){
    bf16x8 a = *(const bf16x8*)&As[w*16+l16][ks*32+quad*8];
    #pragma unroll
    for (int nt=0;nt<4;nt++){
      bf16x8 b = *(const bf16x8*)&Bs[nt*16+l16][ks*32+quad*8];
      acc[nt] = __builtin_amdgcn_mfma_f32_16x16x32_bf16(a,b,acc[nt],0,0,0);
    }
  }
  #pragma unroll
  for (int nt=0;nt<4;nt++)
    #pragma unroll
    for (int i=0;i<4;i++){
      int row = row0 + w*16 + quad*4 + i;
      int col = n0 + nt*16 + l16;
      size_t idx = (size_t)row*DM_ + col;
      if (f32) ((float*)outv)[idx] = acc[nt][i];
      else ((u16*)outv)[idx] = f2b(acc[nt][i]);
    }
}

extern "C" void kernel_launch(void* const* d_in, const int* in_sizes, int n_in,
                              void* d_out, int out_size, void* d_ws, size_t ws_size,
                              hipStream_t stream) {
  const void* x  = d_in[0];
  const void* Wq = d_in[1];
  const void* Wk = d_in[2];
  const void* Wv = d_in[3];
  const void* Wo = d_in[4];
  const void* UL[4] = {d_in[5],d_in[6],d_in[7],d_in[8]};
  const void* VR[4] = {d_in[9],d_in[10],d_in[11],d_in[12]};
  const void* UR[4] = {d_in[13],d_in[14],d_in[15],d_in[16]};
  const void* VL[4] = {d_in[17],d_in[18],d_in[19],d_in[20]};

  int* flag = (int*)d_ws;
  float* ws = (float*)d_ws + 16;
  float* q    = ws;
  float* kf   = q    + (size_t)BT_*64;
  float* vf   = kf   + (size_t)BT_*64;
  float* uLa  = vf   + (size_t)BT_*64;
  float* vRa  = uLa  + (size_t)BT_*88;
  float* vrxa = vRa  + (size_t)BT_*88;
  float* vlxa = vrxa + (size_t)BT_*88;
  float* SL   = vlxa + (size_t)BT_*88;
  float* SP   = SL   + (size_t)B_*NCH_*STATE_;
  float* Y    = SP   + (size_t)B_*NCH_*STATE_;

  k_detect<<<1, 64, 0, stream>>>((const u16*)x, flag);
  k_proj<<<BT_/64, 256, 0, stream>>>(x, Wq, Wk, Wv, q, kf, vf, flag);
  k_prep<<<BT_, 384, 0, stream>>>(q, kf, vf,
      UL[0],UL[1],UL[2],UL[3], VR[0],VR[1],VR[2],VR[3], VL[0],VL[1],VL[2],VL[3],
      uLa, vRa, vrxa, vlxa, flag);
  k_chunksum<<<B_*NCH_, 256, 0, stream>>>(kf, vf, uLa, vRa, SL);
  k_prefix<<<B_, 256, 0, stream>>>(SL, SP);
  k_intra<<<B_*NCH_, 256, 0, stream>>>(q, kf, vf, uLa, vRa, vrxa, vlxa, SP,
      UL[0],UL[1],UL[2],UL[3], UR[0],UR[1],UR[2],UR[3], Y, flag);
  k_outproj<<<dim3(BT_/64, DM_/64), 256, 0, stream>>>(Y, Wo, d_out, flag);
}

// Round 5
// 381.924 us; speedup vs baseline: 1.1024x; 1.0528x over previous
//
#include <hip/hip_runtime.h>
#include <hip/hip_bf16.h>

typedef unsigned short u16;
typedef __attribute__((ext_vector_type(8))) short bf16x8;
typedef __attribute__((ext_vector_type(4))) float f32x4;

#define B_ 8
#define T_ 2048
#define BT_ (B_*T_)
#define DM_ 1024
#define DH_ 64
#define NCH_ 64            // chunks per batch
#define S_ (T_/NCH_)       // 32 steps per chunk
#define STATE_ 896         // leaf 256 + Ws 576 + z 64

__device__ __forceinline__ float b2f(u16 u){ unsigned v=((unsigned)u)<<16; float f; __builtin_memcpy(&f,&v,4); return f; }
__device__ __forceinline__ u16 f2b(float f){ __hip_bfloat16 h=__float2bfloat16(f); u16 u; __builtin_memcpy(&u,&h,2); return u; }

__device__ __forceinline__ float ldin(const void* p, size_t i, int f32){
  return f32 ? ((const float*)p)[i] : b2f(((const u16*)p)[i]);
}

// state layout: leaf [0,256): n*16+i*4+j ; Ws: L0@256, L1@384, L2@640, L3@768 ; z@832
__device__ __forceinline__ void decodeWs(int e, int& ia, int& ib){
  if (e<384){ int o=e-256, n=o>>4; ia=n*4+((o>>2)&3); ib=n*4+(o&3); }
  else if (e<640){ int o=e-384, n=o>>6; ia=32+n*8+((o>>3)&7); ib=32+n*8+(o&7); }
  else if (e<768){ int o=e-640, n=o>>6; ia=64+n*8+((o>>3)&7); ib=64+n*8+(o&7); }
  else { int o=e-768; ia=80+((o>>3)&7); ib=80+(o&7); }
}
__device__ __forceinline__ void decode88(int f, int& l, int& n, int& ri){
  if (f<32){ l=0; n=f>>2; ri=f&3; }
  else if (f<64){ l=1; n=(f-32)>>3; ri=f&7; }
  else if (f<80){ l=2; n=(f-64)>>3; ri=f&7; }
  else { l=3; n=0; ri=f&7; }
}

// ---------------- Kernel 0: dtype detection ----------------
__global__ __launch_bounds__(64) void k_detect(const u16* __restrict__ x, int* __restrict__ flag){
  int tid = threadIdx.x;
  int sane = 0;
  for (int i = tid; i < 4096; i += 64){
    u16 u = x[i];
    int e = (u >> 7) & 0xFF;
    if ((u & 0x7FFF) == 0 || (e >= 100 && e <= 140)) sane++;
  }
  #pragma unroll
  for (int o = 32; o > 0; o >>= 1) sane += __shfl_down(sane, o);
  if (tid == 0) flag[0] = (sane < 3600) ? 1 : 0;
}

// ---------------- Kernel 0b: x -> bf16 cast (skipped if input already bf16) ----
__global__ __launch_bounds__(256) void k_xcast(const void* __restrict__ x, u16* __restrict__ xb,
                                               const int* __restrict__ fl){
  if (!fl[0]) return;   // bf16 input: k_proj2 reads x directly
  size_t t = (size_t)blockIdx.x*256 + threadIdx.x;
  const float* xf = (const float*)x;
  f32x4 v0 = *(const f32x4*)(xf + t*8);
  f32x4 v1 = *(const f32x4*)(xf + t*8 + 4);
  ushort4 o1, o2;
  o1.x=f2b(v0[0]); o1.y=f2b(v0[1]); o1.z=f2b(v0[2]); o1.w=f2b(v0[3]);
  o2.x=f2b(v1[0]); o2.y=f2b(v1[1]); o2.z=f2b(v1[2]); o2.w=f2b(v1[3]);
  *(ushort4*)(xb + t*8) = o1;
  *(ushort4*)(xb + t*8 + 4) = o2;
}

// ---------------- Kernel 0c: W -> MFMA B-fragment layout (bf16) ----------------
// QKV frags: entry e=((m*32+ks)*4+nt)*64+lane ; element j = W_m[ks*32+(lane>>4)*8+j][nt*16+(lane&15)]
// Wo frags:  entry eo=(ks*64+nt)*64+lane      ; element j = Wo[ks*32+(lane>>4)*8+j][nt*16+(lane&15)]
__global__ __launch_bounds__(256) void k_wfrag(
    const void* __restrict__ Wq, const void* __restrict__ Wk, const void* __restrict__ Wv,
    const void* __restrict__ Wo, u16* __restrict__ WF, u16* __restrict__ WoF,
    const int* __restrict__ fl)
{
  const int f32 = fl[0];
  int e = blockIdx.x*256 + threadIdx.x;
  if (e < 24576){
    int m = e >> 13;            // /8192
    int rem = e & 8191;
    int ks = rem >> 8;
    int nt = (rem >> 6) & 3;
    int lane = rem & 63;
    const void* W = (m==0)?Wq:((m==1)?Wk:Wv);
    int kr = ks*32 + (lane>>4)*8;
    int col = nt*16 + (lane&15);
    u16 o[8];
    #pragma unroll
    for (int j=0;j<8;j++) o[j] = f2b(ldin(W, (size_t)(kr+j)*DH_ + col, f32));
    u16* dst = WF + (size_t)e*8;
    #pragma unroll
    for (int j=0;j<8;j++) dst[j] = o[j];
  } else if (e < 32768){
    int eo = e - 24576;
    int ks = eo >> 12;
    int nt = (eo >> 6) & 63;
    int lane = eo & 63;
    int kr = ks*32 + (lane>>4)*8;
    int col = nt*16 + (lane&15);
    u16 o[8];
    #pragma unroll
    for (int j=0;j<8;j++) o[j] = f2b(ldin(Wo, (size_t)(kr+j)*DM_ + col, f32));
    u16* dst = WoF + (size_t)eo*8;
    #pragma unroll
    for (int j=0;j<8;j++) dst[j] = o[j];
  }
}

// ---------------- Kernel 1: QKV projection — no LDS, no barriers ----------------
// 1 wave/block, 32 rows/wave, full K=1024, all 192 out-cols. B-frags precomputed.
__global__ __launch_bounds__(64) void k_proj2(
    const void* __restrict__ x, const u16* __restrict__ xb, const u16* __restrict__ WF,
    float* __restrict__ oq, float* __restrict__ ok_, float* __restrict__ ov,
    const int* __restrict__ fl)
{
  const int f32 = fl[0];
  const int rows0 = blockIdx.x*32;
  const int lane = threadIdx.x;
  const int quad = lane>>4, l16 = lane&15;
  const u16* xa = f32 ? xb : (const u16*)x;
  const size_t rowA0 = (size_t)(rows0 + l16)*DM_;
  const size_t rowA1 = (size_t)(rows0 + 16 + l16)*DM_;

  f32x4 acc[24];
  #pragma unroll
  for (int i=0;i<24;i++) acc[i] = (f32x4){0.f,0.f,0.f,0.f};

  #pragma unroll 2
  for (int ks=0;ks<32;ks++){
    int ko = ks*32 + quad*8;
    bf16x8 a0 = *(const bf16x8*)(xa + rowA0 + ko);
    bf16x8 a1 = *(const bf16x8*)(xa + rowA1 + ko);
    #pragma unroll
    for (int m=0;m<3;m++){
      #pragma unroll
      for (int nt=0;nt<4;nt++){
        bf16x8 b = *(const bf16x8*)(WF + ((size_t)((m*32+ks)*4+nt)*64 + lane)*8);
        acc[m*4+nt]      = __builtin_amdgcn_mfma_f32_16x16x32_bf16(a0,b,acc[m*4+nt],0,0,0);
        acc[12+m*4+nt]   = __builtin_amdgcn_mfma_f32_16x16x32_bf16(a1,b,acc[12+m*4+nt],0,0,0);
      }
    }
  }
  #pragma unroll
  for (int sp=0;sp<2;sp++){
    #pragma unroll
    for (int m=0;m<3;m++){
      float* __restrict__ outp = (m==0)?oq:((m==1)?ok_:ov);
      #pragma unroll
      for (int nt=0;nt<4;nt++){
        #pragma unroll
        for (int i=0;i<4;i++){
          int row = rows0 + sp*16 + quad*4 + i;
          int col = nt*16 + l16;
          float val = acc[sp*12+m*4+nt][i];
          if (m<2) val = (val>0.f)? (val+1.f) : expf(val);  // elu1
          outp[(size_t)row*DH_ + col] = val;
        }
      }
    }
  }
}

// ---------------- Kernel 2: per-token basis projections ----------------
__global__ __launch_bounds__(384) void k_prep(
    const float* __restrict__ gq, const float* __restrict__ gk, const float* __restrict__ gv,
    const void* __restrict__ UL0, const void* __restrict__ UL1, const void* __restrict__ UL2, const void* __restrict__ UL3,
    const void* __restrict__ VR0, const void* __restrict__ VR1, const void* __restrict__ VR2, const void* __restrict__ VR3,
    const void* __restrict__ VL0, const void* __restrict__ VL1, const void* __restrict__ VL2, const void* __restrict__ VL3,
    float* __restrict__ uLa, float* __restrict__ vRa, float* __restrict__ vrxa, float* __restrict__ vlxa,
    const int* __restrict__ fl)
{
  const int f32 = fl[0];
  const int row = blockIdx.x;
  int e = threadIdx.x;
  if (e>=352) return;
  int a=e/88, f=e-a*88;
  int l,n,ri; decode88(f,l,n,ri);
  const int BSl[4]={4,8,16,32}; const int Rl[4]={4,8,8,8};
  int bs=BSl[l], r=Rl[l];
  const float* src = (a==0)? (gk+(size_t)row*64) : (a==1)? (gv+(size_t)row*64) : (gq+(size_t)row*64);
  int off = n*2*bs + ((a==1||a==2)?bs:0);
  const void* U;
  if (a==0)      U = (l==0)?UL0:(l==1)?UL1:(l==2)?UL2:UL3;
  else if (a==3) U = (l==0)?VL0:(l==1)?VL1:(l==2)?VL2:VL3;
  else           U = (l==0)?VR0:(l==1)?VR1:(l==2)?VR2:VR3;
  float acc=0.f;
  for (int d=0; d<bs; d++) acc += src[off+d]*ldin(U, d*r+ri, f32);
  float* dst = (a==0)?uLa:(a==1)?vRa:(a==2)?vrxa:vlxa;
  dst[(size_t)row*88+f] = acc;
}

// ---------------- Kernel 3: per-chunk state sums ----------------
__global__ __launch_bounds__(256) void k_chunksum(
    const float* __restrict__ gk, const float* __restrict__ gv,
    const float* __restrict__ uLa, const float* __restrict__ vRa,
    float* __restrict__ SL)
{
  const int bid = blockIdx.x;
  const int b = bid/NCH_, c = bid%NCH_;
  const size_t base64 = (size_t)(b*T_ + c*S_)*64;
  const size_t base88 = (size_t)(b*T_ + c*S_)*88;
  for (int p=0;p<4;p++){
    int e = threadIdx.x + p*256;
    if (e>=STATE_) break;
    float acc=0.f;
    if (e < 256){
      int n=e>>4;
      const float* A = gk + base64 + n*4 + ((e>>2)&3);
      const float* Bp = gv + base64 + n*4 + (e&3);
      for (int s=0;s<S_;s++) acc += A[s*64]*Bp[s*64];
    } else if (e < 832){
      int ia, ib; decodeWs(e, ia, ib);
      const float* A = uLa + base88 + ia;
      const float* Bp = vRa + base88 + ib;
      for (int s=0;s<S_;s++) acc += A[s*88]*Bp[s*88];
    } else {
      const float* A = gk + base64 + (e-832);
      for (int s=0;s<S_;s++) acc += A[s*64];
    }
    SL[(size_t)bid*STATE_ + e] = acc;
  }
}

// ---------------- Kernel 4: exclusive prefix over chunks ----------------
__global__ __launch_bounds__(256) void k_prefix(const float* __restrict__ SL, float* __restrict__ SP){
  const int b = blockIdx.x;
  for (int p=0;p<4;p++){
    int e = threadIdx.x + p*256;
    if (e>=STATE_) break;
    float run=0.f;
    for (int c=0;c<NCH_;c++){
      size_t idx = ((size_t)(b*NCH_+c))*STATE_ + e;
      SP[idx] = run; run += SL[idx];
    }
  }
}

// ---------------- Kernel 5: parallel intra-chunk ----------------
__global__ __launch_bounds__(256) void k_intra(
    const float* __restrict__ gq, const float* __restrict__ gk, const float* __restrict__ gv,
    const float* __restrict__ uLa, const float* __restrict__ vRa,
    const float* __restrict__ vrxa, const float* __restrict__ vlxa,
    const float* __restrict__ SP,
    const void* __restrict__ UL0, const void* __restrict__ UL1, const void* __restrict__ UL2, const void* __restrict__ UL3,
    const void* __restrict__ UR0, const void* __restrict__ UR1, const void* __restrict__ UR2, const void* __restrict__ UR3,
    u16* __restrict__ Yb, const int* __restrict__ fl)
{
  __shared__ float kS[S_*64];
  __shared__ float vS[S_*64];
  __shared__ float uvS[S_*176];
  __shared__ float st0[STATE_];
  __shared__ float ULs[464], URs[464];
  const int f32 = fl[0];
  const int tid = threadIdx.x;
  const int bid = blockIdx.x;
  const int b = bid/NCH_, c = bid%NCH_;
  const int row0 = b*T_ + c*S_;

  const size_t r64 = (size_t)row0*64;
  for (int i=tid;i<S_*64;i+=256){ kS[i]=gk[r64+i]; vS[i]=gv[r64+i]; }
  const size_t r88 = (size_t)row0*88;
  for (int i=tid;i<S_*88;i+=256){
    int s=i/88, f=i-s*88;
    uvS[s*176+f]    = uLa[r88+i];
    uvS[s*176+88+f] = vRa[r88+i];
  }
  for (int e=tid;e<STATE_;e+=256) st0[e] = SP[(size_t)bid*STATE_+e];
  for (int e=tid;e<464;e+=256){
    int l, idx;
    if (e<16){ l=0; idx=e; } else if (e<80){ l=1; idx=e-16; }
    else if (e<208){ l=2; idx=e-80; } else { l=3; idx=e-208; }
    const void* ul = (l==0)?UL0:(l==1)?UL1:(l==2)?UL2:UL3;
    const void* ur = (l==0)?UR0:(l==1)?UR1:(l==2)?UR2:UR3;
    ULs[e] = ldin(ul, idx, f32); URs[e] = ldin(ur, idx, f32);
  }
  __syncthreads();

  const int w = tid>>6, lane = tid&63, tl = lane>>3, g = lane&7;
  const int t = w*8 + tl;
  const int n1 = g>>1, ri1 = (g&1)*4;
  const int n2 = g>>2, ri2 = (g&3)*2;
  const size_t row = (size_t)(row0 + t);

  float qr[8];
  { const float* qp = gq + row*64 + g*8;
    *(f32x4*)&qr[0] = *(const f32x4*)qp; *(f32x4*)&qr[4] = *(const f32x4*)(qp+4); }
  float rxL0[4], lxL0[4], rxL1[8], lxL1[8], rxL2[8], lxL2[8], rxL3[8], lxL3[8];
  { const float* rp = vrxa + row*88; const float* lp = vlxa + row*88;
    *(f32x4*)&rxL0[0] = *(const f32x4*)(rp + 4*g);
    *(f32x4*)&lxL0[0] = *(const f32x4*)(lp + 4*g);
    *(f32x4*)&rxL1[0] = *(const f32x4*)(rp + 32 + n1*8); *(f32x4*)&rxL1[4] = *(const f32x4*)(rp + 36 + n1*8);
    *(f32x4*)&lxL1[0] = *(const f32x4*)(lp + 32 + n1*8); *(f32x4*)&lxL1[4] = *(const f32x4*)(lp + 36 + n1*8);
    *(f32x4*)&rxL2[0] = *(const f32x4*)(rp + 64 + n2*8); *(f32x4*)&rxL2[4] = *(const f32x4*)(rp + 68 + n2*8);
    *(f32x4*)&lxL2[0] = *(const f32x4*)(lp + 64 + n2*8); *(f32x4*)&lxL2[4] = *(const f32x4*)(lp + 68 + n2*8);
    *(f32x4*)&rxL3[0] = *(const f32x4*)(rp + 80); *(f32x4*)&rxL3[4] = *(const f32x4*)(rp + 84);
    *(f32x4*)&lxL3[0] = *(const f32x4*)(lp + 80); *(f32x4*)&lxL3[4] = *(const f32x4*)(lp + 84); }

  float yacc[8], den = 0.f;
  #pragma unroll
  for (int cc=0;cc<8;cc++){
    int n = 2*g + (cc>>2);
    const float* m = &st0[n*16 + (cc&3)*4];
    const float* qp = &qr[(cc>>2)*4];
    yacc[cc] = m[0]*qp[0]+m[1]*qp[1]+m[2]*qp[2]+m[3]*qp[3];
    den += st0[832 + g*8 + cc]*qr[cc];
  }
  float gtL0[4], gbL0[4], gtL1[4], gbL1[4], gtL2[2], gbL2[2], gtL3, gbL3;
  #pragma unroll
  for (int cc=0;cc<4;cc++){
    const float* m = &st0[256 + g*16 + cc*4];
    gtL0[cc] = m[0]*rxL0[0]+m[1]*rxL0[1]+m[2]*rxL0[2]+m[3]*rxL0[3];
    float s2 = 0.f;
    #pragma unroll
    for (int j=0;j<4;j++) s2 += st0[256 + g*16 + j*4 + cc]*lxL0[j];
    gbL0[cc] = s2;
  }
  #pragma unroll
  for (int cc=0;cc<4;cc++){
    int ri = ri1 + cc;
    float s1=0.f, s2=0.f;
    #pragma unroll
    for (int j=0;j<8;j++){
      s1 += st0[384 + n1*64 + ri*8 + j]*rxL1[j];
      s2 += st0[384 + n1*64 + j*8 + ri]*lxL1[j];
    }
    gtL1[cc]=s1; gbL1[cc]=s2;
  }
  #pragma unroll
  for (int cc=0;cc<2;cc++){
    int ri = ri2 + cc;
    float s1=0.f, s2=0.f;
    #pragma unroll
    for (int j=0;j<8;j++){
      s1 += st0[640 + n2*64 + ri*8 + j]*rxL2[j];
      s2 += st0[640 + n2*64 + j*8 + ri]*lxL2[j];
    }
    gtL2[cc]=s1; gbL2[cc]=s2;
  }
  { float s1=0.f, s2=0.f;
    #pragma unroll
    for (int j=0;j<8;j++){
      s1 += st0[768 + g*8 + j]*rxL3[j];
      s2 += st0[768 + j*8 + g]*lxL3[j];
    }
    gtL3=s1; gbL3=s2; }

  const int smax = w*8 + 8;
  for (int s=0; s<smax; s++){
    const float* ks_ = &kS[s*64 + g*8];
    const float* vs_ = &vS[s*64 + g*8];
    const float* uL_ = &uvS[s*176];
    const float* vR_ = &uvS[s*176 + 88];
    float dv0 = vs_[0]*qr[0]+vs_[1]*qr[1]+vs_[2]*qr[2]+vs_[3]*qr[3];
    float dv1 = vs_[4]*qr[4]+vs_[5]*qr[5]+vs_[6]*qr[6]+vs_[7]*qr[7];
    float dn = 0.f;
    #pragma unroll
    for (int cc=0;cc<8;cc++) dn += ks_[cc]*qr[cc];
    float d1L0=0.f,d2L0=0.f;
    #pragma unroll
    for (int j=0;j<4;j++){ d1L0 += vR_[4*g+j]*rxL0[j]; d2L0 += uL_[4*g+j]*lxL0[j]; }
    float d1L1=0.f,d2L1=0.f;
    #pragma unroll
    for (int j=0;j<8;j++){ d1L1 += vR_[32+n1*8+j]*rxL1[j]; d2L1 += uL_[32+n1*8+j]*lxL1[j]; }
    float d1L2=0.f,d2L2=0.f;
    #pragma unroll
    for (int j=0;j<8;j++){ d1L2 += vR_[64+n2*8+j]*rxL2[j]; d2L2 += uL_[64+n2*8+j]*lxL2[j]; }
    float d1L3=0.f,d2L3=0.f;
    #pragma unroll
    for (int j=0;j<8;j++){ d1L3 += vR_[80+j]*rxL3[j]; d2L3 += uL_[80+j]*lxL3[j]; }
    if (s<=t){
      den += dn;
      #pragma unroll
      for (int cc=0;cc<8;cc++) yacc[cc] += ks_[cc]*((cc<4)?dv0:dv1);
      #pragma unroll
      for (int cc=0;cc<4;cc++){
        gtL0[cc] += uL_[4*g+cc]*d1L0;          gbL0[cc] += vR_[4*g+cc]*d2L0;
        gtL1[cc] += uL_[32+n1*8+ri1+cc]*d1L1;  gbL1[cc] += vR_[32+n1*8+ri1+cc]*d2L1;
      }
      #pragma unroll
      for (int cc=0;cc<2;cc++){
        gtL2[cc] += uL_[64+n2*8+ri2+cc]*d1L2;  gbL2[cc] += vR_[64+n2*8+ri2+cc]*d2L2;
      }
      gtL3 += uL_[80+g]*d1L3;  gbL3 += vR_[80+g]*d2L3;
    }
  }
  __syncthreads();

  { float* gr = &uvS[t*176];
    #pragma unroll
    for (int cc=0;cc<4;cc++){
      gr[4*g+cc] = gtL0[cc];                 gr[88+4*g+cc] = gbL0[cc];
      gr[32+n1*8+ri1+cc] = gtL1[cc];         gr[88+32+n1*8+ri1+cc] = gbL1[cc];
    }
    #pragma unroll
    for (int cc=0;cc<2;cc++){
      gr[64+n2*8+ri2+cc] = gtL2[cc];         gr[88+64+n2*8+ri2+cc] = gbL2[cc];
    }
    gr[80+g] = gtL3;  gr[88+80+g] = gbL3;
  }
  __syncthreads();

  den += __shfl_xor(den,1); den += __shfl_xor(den,2); den += __shfl_xor(den,4);
  float inv = 1.f / fmaxf(den, 1e-6f);
  const float* gr = &uvS[t*176];
  float yout[8];
  #pragma unroll
  for (int cc=0;cc<8;cc++){
    int j = g*8 + cc;
    float y = yacc[cc];
    if (cc<4){
      #pragma unroll
      for (int rr=0;rr<4;rr++) y += ULs[cc*4+rr]*gr[g*4+rr];
    } else {
      #pragma unroll
      for (int rr=0;rr<4;rr++) y += URs[(cc-4)*4+rr]*gr[88+g*4+rr];
    }
    { int seg=j>>4, pos=j&15;
      if (pos<8){
        #pragma unroll
        for (int rr=0;rr<8;rr++) y += ULs[16+pos*8+rr]*gr[32+seg*8+rr];
      } else {
        #pragma unroll
        for (int rr=0;rr<8;rr++) y += URs[16+(pos-8)*8+rr]*gr[88+32+seg*8+rr];
      } }
    { int seg=j>>5, pos=j&31;
      if (pos<16){
        #pragma unroll
        for (int rr=0;rr<8;rr++) y += ULs[80+pos*8+rr]*gr[64+seg*8+rr];
      } else {
        #pragma unroll
        for (int rr=0;rr<8;rr++) y += URs[80+(pos-16)*8+rr]*gr[88+64+seg*8+rr];
      } }
    { int pos=j;
      if (pos<32){
        #pragma unroll
        for (int rr=0;rr<8;rr++) y += ULs[208+pos*8+rr]*gr[80+rr];
      } else {
        #pragma unroll
        for (int rr=0;rr<8;rr++) y += URs[208+(pos-32)*8+rr]*gr[88+80+rr];
      } }
    yout[cc] = y*inv;
  }
  u16* yp = Yb + row*64 + g*8;
  ushort4 o1, o2;
  o1.x=f2b(yout[0]); o1.y=f2b(yout[1]); o1.z=f2b(yout[2]); o1.w=f2b(yout[3]);
  o2.x=f2b(yout[4]); o2.y=f2b(yout[5]); o2.z=f2b(yout[6]); o2.w=f2b(yout[7]);
  *(ushort4*)yp = o1;
  *(ushort4*)(yp+4) = o2;
}

// ---------------- Kernel 6: output projection — no LDS, no barriers ----------------
// 1 wave/block, 32 rows × 256 cols per wave; Wo fragments precomputed; Y is bf16.
__global__ __launch_bounds__(64) void k_outproj2(
    const u16* __restrict__ Yb, const u16* __restrict__ WoF, void* __restrict__ outv,
    const int* __restrict__ fl)
{
  const int f32 = fl[0];
  const int rows0 = blockIdx.x*32;
  const int nt0 = blockIdx.y*16;
  const int lane = threadIdx.x;
  const int quad = lane>>4, l16 = lane&15;

  f32x4 acc[32];
  #pragma unroll
  for (int i=0;i<32;i++) acc[i] = (f32x4){0.f,0.f,0.f,0.f};

  #pragma unroll
  for (int ks=0;ks<2;ks++){
    int ko = ks*32 + quad*8;
    bf16x8 a0 = *(const bf16x8*)(Yb + (size_t)(rows0 + l16)*DH_ + ko);
    bf16x8 a1 = *(const bf16x8*)(Yb + (size_t)(rows0 + 16 + l16)*DH_ + ko);
    #pragma unroll
    for (int nt=0;nt<16;nt++){
      bf16x8 b = *(const bf16x8*)(WoF + ((size_t)(ks*64 + nt0 + nt)*64 + lane)*8);
      acc[nt]    = __builtin_amdgcn_mfma_f32_16x16x32_bf16(a0,b,acc[nt],0,0,0);
      acc[16+nt] = __builtin_amdgcn_mfma_f32_16x16x32_bf16(a1,b,acc[16+nt],0,0,0);
    }
  }
  #pragma unroll
  for (int sp=0;sp<2;sp++){
    #pragma unroll
    for (int nt=0;nt<16;nt++){
      #pragma unroll
      for (int i=0;i<4;i++){
        int row = rows0 + sp*16 + quad*4 + i;
        int col = (nt0+nt)*16 + l16;
        size_t idx = (size_t)row*DM_ + col;
        float v = acc[sp*16+nt][i];
        if (f32) ((float*)outv)[idx] = v;
        else ((u16*)outv)[idx] = f2b(v);
      }
    }
  }
}

extern "C" void kernel_launch(void* const* d_in, const int* in_sizes, int n_in,
                              void* d_out, int out_size, void* d_ws, size_t ws_size,
                              hipStream_t stream) {
  const void* x  = d_in[0];
  const void* Wq = d_in[1];
  const void* Wk = d_in[2];
  const void* Wv = d_in[3];
  const void* Wo = d_in[4];
  const void* UL[4] = {d_in[5],d_in[6],d_in[7],d_in[8]};
  const void* VR[4] = {d_in[9],d_in[10],d_in[11],d_in[12]};
  const void* UR[4] = {d_in[13],d_in[14],d_in[15],d_in[16]};
  const void* VL[4] = {d_in[17],d_in[18],d_in[19],d_in[20]};

  int* flag = (int*)d_ws;
  float* ws = (float*)d_ws + 16;
  float* q    = ws;
  float* kf   = q    + (size_t)BT_*64;
  float* vf   = kf   + (size_t)BT_*64;
  float* uLa  = vf   + (size_t)BT_*64;
  float* vRa  = uLa  + (size_t)BT_*88;
  float* vrxa = vRa  + (size_t)BT_*88;
  float* vlxa = vrxa + (size_t)BT_*88;
  float* SL   = vlxa + (size_t)BT_*88;
  float* SP   = SL   + (size_t)B_*NCH_*STATE_;
  u16*   Yb   = (u16*)(SP + (size_t)B_*NCH_*STATE_);
  u16*   xb   = Yb + (size_t)BT_*64;
  u16*   WF   = xb + (size_t)BT_*DM_;
  u16*   WoF  = WF + (size_t)196608;

  k_detect<<<1, 64, 0, stream>>>((const u16*)x, flag);
  k_xcast<<<8192, 256, 0, stream>>>(x, xb, flag);
  k_wfrag<<<128, 256, 0, stream>>>(Wq, Wk, Wv, Wo, WF, WoF, flag);
  k_proj2<<<512, 64, 0, stream>>>(x, xb, WF, q, kf, vf, flag);
  k_prep<<<BT_, 384, 0, stream>>>(q, kf, vf,
      UL[0],UL[1],UL[2],UL[3], VR[0],VR[1],VR[2],VR[3], VL[0],VL[1],VL[2],VL[3],
      uLa, vRa, vrxa, vlxa, flag);
  k_chunksum<<<B_*NCH_, 256, 0, stream>>>(kf, vf, uLa, vRa, SL);
  k_prefix<<<B_, 256, 0, stream>>>(SL, SP);
  k_intra<<<B_*NCH_, 256, 0, stream>>>(q, kf, vf, uLa, vRa, vrxa, vlxa, SP,
      UL[0],UL[1],UL[2],UL[3], UR[0],UR[1],UR[2],UR[3], Yb, flag);
  k_outproj2<<<dim3(512, 4), 64, 0, stream>>>(Yb, WoF, d_out, flag);
}

// Round 6
// 313.417 us; speedup vs baseline: 1.3433x; 1.2186x over previous
//
#include <hip/hip_runtime.h>
#include <hip/hip_bf16.h>

typedef unsigned short u16;
typedef __attribute__((ext_vector_type(8))) short bf16x8;
typedef __attribute__((ext_vector_type(4))) float f32x4;

#define B_ 8
#define T_ 2048
#define BT_ (B_*T_)
#define DM_ 1024
#define DH_ 64
#define NCH_ 64            // chunks per batch
#define S_ (T_/NCH_)       // 32 steps per chunk
#define STATE_ 896         // leaf 256 + Ws 576 + z 64

__device__ __forceinline__ float b2f(u16 u){ unsigned v=((unsigned)u)<<16; float f; __builtin_memcpy(&f,&v,4); return f; }
__device__ __forceinline__ u16 f2b(float f){ __hip_bfloat16 h=__float2bfloat16(f); u16 u; __builtin_memcpy(&u,&h,2); return u; }

__device__ __forceinline__ float ldin(const void* p, size_t i, int f32){
  return f32 ? ((const float*)p)[i] : b2f(((const u16*)p)[i]);
}
// load 8 consecutive elements as bf16x8 (converting from fp32 if needed)
__device__ __forceinline__ bf16x8 ld8bf(const void* p, size_t i, int f32){
  if (f32){
    f32x4 v0 = *(const f32x4*)((const float*)p + i);
    f32x4 v1 = *(const f32x4*)((const float*)p + i + 4);
    bf16x8 r;
    #pragma unroll
    for (int j=0;j<4;j++){ r[j] = (short)f2b(v0[j]); r[4+j] = (short)f2b(v1[j]); }
    return r;
  }
  return *(const bf16x8*)((const u16*)p + i);
}

// state layout: leaf [0,256): n*16+i*4+j ; Ws: L0@256, L1@384, L2@640, L3@768 ; z@832
__device__ __forceinline__ void decodeWs(int e, int& ia, int& ib){
  if (e<384){ int o=e-256, n=o>>4; ia=n*4+((o>>2)&3); ib=n*4+(o&3); }
  else if (e<640){ int o=e-384, n=o>>6; ia=32+n*8+((o>>3)&7); ib=32+n*8+(o&7); }
  else if (e<768){ int o=e-640, n=o>>6; ia=64+n*8+((o>>3)&7); ib=64+n*8+(o&7); }
  else { int o=e-768; ia=80+((o>>3)&7); ib=80+(o&7); }
}
__device__ __forceinline__ void decode88(int f, int& l, int& n, int& ri){
  if (f<32){ l=0; n=f>>2; ri=f&3; }
  else if (f<64){ l=1; n=(f-32)>>3; ri=f&7; }
  else if (f<80){ l=2; n=(f-64)>>3; ri=f&7; }
  else { l=3; n=0; ri=f&7; }
}

// ---------------- Kernel 0: dtype detection ----------------
__global__ __launch_bounds__(64) void k_detect(const u16* __restrict__ x, int* __restrict__ flag){
  int tid = threadIdx.x;
  int sane = 0;
  for (int i = tid; i < 4096; i += 64){
    u16 u = x[i];
    int e = (u >> 7) & 0xFF;
    if ((u & 0x7FFF) == 0 || (e >= 100 && e <= 140)) sane++;
  }
  #pragma unroll
  for (int o = 32; o > 0; o >>= 1) sane += __shfl_down(sane, o);
  if (tid == 0) flag[0] = (sane < 3600) ? 1 : 0;
}

// ---------------- Kernel 0c: weight/basis -> MFMA B-fragment layout (bf16) ------
// QKV frags: e=((m*32+ks)*4+nt)*64+lane ; elem j = W_m[ks*32+(lane>>4)*8+j][nt*16+(lane&15)]
// Wo frags:  eo=(ks*64+nt)*64+lane      ; elem j = Wo[...][...]
// Prep frags: pe=((mat*2+ks)*6+nt)*64+lane over 64x96 matrices {Mu(UL),Mv(VR),Mlx(VL)}
__global__ __launch_bounds__(256) void k_wfrag(
    const void* __restrict__ Wq, const void* __restrict__ Wk, const void* __restrict__ Wv,
    const void* __restrict__ Wo,
    const void* __restrict__ UL0, const void* __restrict__ UL1, const void* __restrict__ UL2, const void* __restrict__ UL3,
    const void* __restrict__ VR0, const void* __restrict__ VR1, const void* __restrict__ VR2, const void* __restrict__ VR3,
    const void* __restrict__ VL0, const void* __restrict__ VL1, const void* __restrict__ VL2, const void* __restrict__ VL3,
    u16* __restrict__ WF, u16* __restrict__ WoF, u16* __restrict__ PF,
    const int* __restrict__ fl)
{
  const int f32 = fl[0];
  int e = blockIdx.x*256 + threadIdx.x;
  if (e < 24576){
    int m = e >> 13;
    int rem = e & 8191;
    int ks = rem >> 8;
    int nt = (rem >> 6) & 3;
    int lane = rem & 63;
    const void* W = (m==0)?Wq:((m==1)?Wk:Wv);
    int kr = ks*32 + (lane>>4)*8;
    int col = nt*16 + (lane&15);
    u16 o[8];
    #pragma unroll
    for (int j=0;j<8;j++) o[j] = f2b(ldin(W, (size_t)(kr+j)*DH_ + col, f32));
    u16* dst = WF + (size_t)e*8;
    #pragma unroll
    for (int j=0;j<8;j++) dst[j] = o[j];
  } else if (e < 32768){
    int eo = e - 24576;
    int ks = eo >> 12;
    int nt = (eo >> 6) & 63;
    int lane = eo & 63;
    int kr = ks*32 + (lane>>4)*8;
    int col = nt*16 + (lane&15);
    u16 o[8];
    #pragma unroll
    for (int j=0;j<8;j++) o[j] = f2b(ldin(Wo, (size_t)(kr+j)*DM_ + col, f32));
    u16* dst = WoF + (size_t)eo*8;
    #pragma unroll
    for (int j=0;j<8;j++) dst[j] = o[j];
  } else if (e < 35072){
    int pe = e - 32768;         // 0..2303
    int lane = pe & 63;
    int nt = (pe >> 6) % 6;
    int mk = pe / 384;          // mat*2+ks
    int ks = mk & 1, mat = mk >> 1;
    int col = nt*16 + (lane&15);
    int dbase = ks*32 + (lane>>4)*8;
    const int BSl[4]={4,8,16,32}; const int Rl[4]={4,8,8,8};
    u16 o[8];
    #pragma unroll
    for (int j=0;j<8;j++){
      float val = 0.f;
      if (col < 88){
        int l,n,ri; decode88(col,l,n,ri);
        int bs=BSl[l], r=Rl[l];
        int lo = n*2*bs + ((mat==1)?bs:0);
        int d = dbase + j;
        if (d >= lo && d < lo+bs){
          const void* Up;
          if (mat==0)      Up = (l==0)?UL0:(l==1)?UL1:(l==2)?UL2:UL3;
          else if (mat==1) Up = (l==0)?VR0:(l==1)?VR1:(l==2)?VR2:VR3;
          else             Up = (l==0)?VL0:(l==1)?VL1:(l==2)?VL2:VL3;
          val = ldin(Up, (size_t)(d-lo)*r + ri, f32);
        }
      }
      o[j] = f2b(val);
    }
    u16* dst = PF + (size_t)pe*8;
    #pragma unroll
    for (int j=0;j<8;j++) dst[j] = o[j];
  }
}

// ---------------- Kernel 1: QKV projection — no LDS, no barriers ----------------
// 1 wave/block, 32 rows/wave, K=1024, 192 out-cols. Also emits bf16 q/k/v.
__global__ __launch_bounds__(64) void k_proj2(
    const void* __restrict__ x, const u16* __restrict__ WF,
    float* __restrict__ oq, float* __restrict__ ok_, float* __restrict__ ov,
    u16* __restrict__ qb16, u16* __restrict__ kb16, u16* __restrict__ vb16,
    const int* __restrict__ fl)
{
  const int f32 = fl[0];
  const int rows0 = blockIdx.x*32;
  const int lane = threadIdx.x;
  const int quad = lane>>4, l16 = lane&15;
  const size_t rowA0 = (size_t)(rows0 + l16)*DM_;
  const size_t rowA1 = (size_t)(rows0 + 16 + l16)*DM_;

  f32x4 acc[24];
  #pragma unroll
  for (int i=0;i<24;i++) acc[i] = (f32x4){0.f,0.f,0.f,0.f};

  #pragma unroll 2
  for (int ks=0;ks<32;ks++){
    int ko = ks*32 + quad*8;
    bf16x8 a0 = ld8bf(x, rowA0 + ko, f32);
    bf16x8 a1 = ld8bf(x, rowA1 + ko, f32);
    #pragma unroll
    for (int m=0;m<3;m++){
      #pragma unroll
      for (int nt=0;nt<4;nt++){
        bf16x8 b = *(const bf16x8*)(WF + ((size_t)((m*32+ks)*4+nt)*64 + lane)*8);
        acc[m*4+nt]      = __builtin_amdgcn_mfma_f32_16x16x32_bf16(a0,b,acc[m*4+nt],0,0,0);
        acc[12+m*4+nt]   = __builtin_amdgcn_mfma_f32_16x16x32_bf16(a1,b,acc[12+m*4+nt],0,0,0);
      }
    }
  }
  #pragma unroll
  for (int sp=0;sp<2;sp++){
    #pragma unroll
    for (int m=0;m<3;m++){
      float* __restrict__ outp = (m==0)?oq:((m==1)?ok_:ov);
      u16* __restrict__ outb = (m==0)?qb16:((m==1)?kb16:vb16);
      #pragma unroll
      for (int nt=0;nt<4;nt++){
        #pragma unroll
        for (int i=0;i<4;i++){
          int row = rows0 + sp*16 + quad*4 + i;
          int col = nt*16 + l16;
          float val = acc[sp*12+m*4+nt][i];
          if (m<2) val = (val>0.f)? (val+1.f) : expf(val);  // elu1
          outp[(size_t)row*DH_ + col] = val;
          outb[(size_t)row*DH_ + col] = f2b(val);
        }
      }
    }
  }
}

// ---------------- Kernel 2: basis projections via MFMA — no LDS, no barriers ----
// 16 rows/block (1 wave). uL=K@Mu, vR=V@Mv, vrx=Q@Mv, vlx=Q@Mlx  (N padded 88->96)
__global__ __launch_bounds__(64) void k_prep2(
    const u16* __restrict__ qb16, const u16* __restrict__ kb16, const u16* __restrict__ vb16,
    const u16* __restrict__ PF,
    float* __restrict__ uLa, float* __restrict__ vRa, float* __restrict__ vrxa, float* __restrict__ vlxa)
{
  const int rows0 = blockIdx.x*16;
  const int lane = threadIdx.x;
  const int quad = lane>>4, l16 = lane&15;

  bf16x8 ak[2], av[2], aq[2];
  #pragma unroll
  for (int ks=0;ks<2;ks++){
    size_t off = (size_t)(rows0 + l16)*DH_ + ks*32 + quad*8;
    ak[ks] = *(const bf16x8*)(kb16 + off);
    av[ks] = *(const bf16x8*)(vb16 + off);
    aq[ks] = *(const bf16x8*)(qb16 + off);
  }
  f32x4 acc[4][6];
  #pragma unroll
  for (int m=0;m<4;m++)
    #pragma unroll
    for (int nt=0;nt<6;nt++) acc[m][nt] = (f32x4){0.f,0.f,0.f,0.f};

  #pragma unroll
  for (int ks=0;ks<2;ks++){
    #pragma unroll
    for (int nt=0;nt<6;nt++){
      bf16x8 bu = *(const bf16x8*)(PF + ((size_t)((0*2+ks)*6+nt)*64 + lane)*8);
      bf16x8 bv = *(const bf16x8*)(PF + ((size_t)((1*2+ks)*6+nt)*64 + lane)*8);
      bf16x8 bl = *(const bf16x8*)(PF + ((size_t)((2*2+ks)*6+nt)*64 + lane)*8);
      acc[0][nt] = __builtin_amdgcn_mfma_f32_16x16x32_bf16(ak[ks], bu, acc[0][nt],0,0,0);
      acc[1][nt] = __builtin_amdgcn_mfma_f32_16x16x32_bf16(av[ks], bv, acc[1][nt],0,0,0);
      acc[2][nt] = __builtin_amdgcn_mfma_f32_16x16x32_bf16(aq[ks], bv, acc[2][nt],0,0,0);
      acc[3][nt] = __builtin_amdgcn_mfma_f32_16x16x32_bf16(aq[ks], bl, acc[3][nt],0,0,0);
    }
  }
  #pragma unroll
  for (int m=0;m<4;m++){
    float* __restrict__ dst = (m==0)?uLa:(m==1)?vRa:(m==2)?vrxa:vlxa;
    #pragma unroll
    for (int nt=0;nt<6;nt++){
      int col = nt*16 + l16;
      if (col < 88){
        #pragma unroll
        for (int i=0;i<4;i++){
          int row = rows0 + quad*4 + i;
          dst[(size_t)row*88 + col] = acc[m][nt][i];
        }
      }
    }
  }
}

// ---------------- Kernel 3: per-chunk state sums ----------------
__global__ __launch_bounds__(256) void k_chunksum(
    const float* __restrict__ gk, const float* __restrict__ gv,
    const float* __restrict__ uLa, const float* __restrict__ vRa,
    float* __restrict__ SL)
{
  const int bid = blockIdx.x;
  const int b = bid/NCH_, c = bid%NCH_;
  const size_t base64 = (size_t)(b*T_ + c*S_)*64;
  const size_t base88 = (size_t)(b*T_ + c*S_)*88;
  for (int p=0;p<4;p++){
    int e = threadIdx.x + p*256;
    if (e>=STATE_) break;
    float acc=0.f;
    if (e < 256){
      int n=e>>4;
      const float* A = gk + base64 + n*4 + ((e>>2)&3);
      const float* Bp = gv + base64 + n*4 + (e&3);
      for (int s=0;s<S_;s++) acc += A[s*64]*Bp[s*64];
    } else if (e < 832){
      int ia, ib; decodeWs(e, ia, ib);
      const float* A = uLa + base88 + ia;
      const float* Bp = vRa + base88 + ib;
      for (int s=0;s<S_;s++) acc += A[s*88]*Bp[s*88];
    } else {
      const float* A = gk + base64 + (e-832);
      for (int s=0;s<S_;s++) acc += A[s*64];
    }
    SL[(size_t)bid*STATE_ + e] = acc;
  }
}

// ---------------- Kernel 4: exclusive prefix over chunks ----------------
__global__ __launch_bounds__(256) void k_prefix(const float* __restrict__ SL, float* __restrict__ SP){
  const int b = blockIdx.x;
  for (int p=0;p<4;p++){
    int e = threadIdx.x + p*256;
    if (e>=STATE_) break;
    float run=0.f;
    for (int c=0;c<NCH_;c++){
      size_t idx = ((size_t)(b*NCH_+c))*STATE_ + e;
      SP[idx] = run; run += SL[idx];
    }
  }
}

// ---------------- Kernel 5: parallel intra-chunk ----------------
__global__ __launch_bounds__(256) void k_intra(
    const float* __restrict__ gq, const float* __restrict__ gk, const float* __restrict__ gv,
    const float* __restrict__ uLa, const float* __restrict__ vRa,
    const float* __restrict__ vrxa, const float* __restrict__ vlxa,
    const float* __restrict__ SP,
    const void* __restrict__ UL0, const void* __restrict__ UL1, const void* __restrict__ UL2, const void* __restrict__ UL3,
    const void* __restrict__ UR0, const void* __restrict__ UR1, const void* __restrict__ UR2, const void* __restrict__ UR3,
    u16* __restrict__ Yb, const int* __restrict__ fl)
{
  __shared__ float kS[S_*64];
  __shared__ float vS[S_*64];
  __shared__ float uvS[S_*176];
  __shared__ float st0[STATE_];
  __shared__ float ULs[464], URs[464];
  const int f32 = fl[0];
  const int tid = threadIdx.x;
  const int bid = blockIdx.x;
  const int b = bid/NCH_, c = bid%NCH_;
  const int row0 = b*T_ + c*S_;

  const size_t r64 = (size_t)row0*64;
  for (int i=tid;i<S_*64;i+=256){ kS[i]=gk[r64+i]; vS[i]=gv[r64+i]; }
  const size_t r88 = (size_t)row0*88;
  for (int i=tid;i<S_*88;i+=256){
    int s=i/88, f=i-s*88;
    uvS[s*176+f]    = uLa[r88+i];
    uvS[s*176+88+f] = vRa[r88+i];
  }
  for (int e=tid;e<STATE_;e+=256) st0[e] = SP[(size_t)bid*STATE_+e];
  for (int e=tid;e<464;e+=256){
    int l, idx;
    if (e<16){ l=0; idx=e; } else if (e<80){ l=1; idx=e-16; }
    else if (e<208){ l=2; idx=e-80; } else { l=3; idx=e-208; }
    const void* ul = (l==0)?UL0:(l==1)?UL1:(l==2)?UL2:UL3;
    const void* ur = (l==0)?UR0:(l==1)?UR1:(l==2)?UR2:UR3;
    ULs[e] = ldin(ul, idx, f32); URs[e] = ldin(ur, idx, f32);
  }
  __syncthreads();

  const int w = tid>>6, lane = tid&63, tl = lane>>3, g = lane&7;
  const int t = w*8 + tl;
  const int n1 = g>>1, ri1 = (g&1)*4;
  const int n2 = g>>2, ri2 = (g&3)*2;
  const size_t row = (size_t)(row0 + t);

  float qr[8];
  { const float* qp = gq + row*64 + g*8;
    *(f32x4*)&qr[0] = *(const f32x4*)qp; *(f32x4*)&qr[4] = *(const f32x4*)(qp+4); }
  float rxL0[4], lxL0[4], rxL1[8], lxL1[8], rxL2[8], lxL2[8], rxL3[8], lxL3[8];
  { const float* rp = vrxa + row*88; const float* lp = vlxa + row*88;
    *(f32x4*)&rxL0[0] = *(const f32x4*)(rp + 4*g);
    *(f32x4*)&lxL0[0] = *(const f32x4*)(lp + 4*g);
    *(f32x4*)&rxL1[0] = *(const f32x4*)(rp + 32 + n1*8); *(f32x4*)&rxL1[4] = *(const f32x4*)(rp + 36 + n1*8);
    *(f32x4*)&lxL1[0] = *(const f32x4*)(lp + 32 + n1*8); *(f32x4*)&lxL1[4] = *(const f32x4*)(lp + 36 + n1*8);
    *(f32x4*)&rxL2[0] = *(const f32x4*)(rp + 64 + n2*8); *(f32x4*)&rxL2[4] = *(const f32x4*)(rp + 68 + n2*8);
    *(f32x4*)&lxL2[0] = *(const f32x4*)(lp + 64 + n2*8); *(f32x4*)&lxL2[4] = *(const f32x4*)(lp + 68 + n2*8);
    *(f32x4*)&rxL3[0] = *(const f32x4*)(rp + 80); *(f32x4*)&rxL3[4] = *(const f32x4*)(rp + 84);
    *(f32x4*)&lxL3[0] = *(const f32x4*)(lp + 80); *(f32x4*)&lxL3[4] = *(const f32x4*)(lp + 84); }

  float yacc[8], den = 0.f;
  #pragma unroll
  for (int cc=0;cc<8;cc++){
    int n = 2*g + (cc>>2);
    const float* m = &st0[n*16 + (cc&3)*4];
    const float* qp = &qr[(cc>>2)*4];
    yacc[cc] = m[0]*qp[0]+m[1]*qp[1]+m[2]*qp[2]+m[3]*qp[3];
    den += st0[832 + g*8 + cc]*qr[cc];
  }
  float gtL0[4], gbL0[4], gtL1[4], gbL1[4], gtL2[2], gbL2[2], gtL3, gbL3;
  #pragma unroll
  for (int cc=0;cc<4;cc++){
    const float* m = &st0[256 + g*16 + cc*4];
    gtL0[cc] = m[0]*rxL0[0]+m[1]*rxL0[1]+m[2]*rxL0[2]+m[3]*rxL0[3];
    float s2 = 0.f;
    #pragma unroll
    for (int j=0;j<4;j++) s2 += st0[256 + g*16 + j*4 + cc]*lxL0[j];
    gbL0[cc] = s2;
  }
  #pragma unroll
  for (int cc=0;cc<4;cc++){
    int ri = ri1 + cc;
    float s1=0.f, s2=0.f;
    #pragma unroll
    for (int j=0;j<8;j++){
      s1 += st0[384 + n1*64 + ri*8 + j]*rxL1[j];
      s2 += st0[384 + n1*64 + j*8 + ri]*lxL1[j];
    }
    gtL1[cc]=s1; gbL1[cc]=s2;
  }
  #pragma unroll
  for (int cc=0;cc<2;cc++){
    int ri = ri2 + cc;
    float s1=0.f, s2=0.f;
    #pragma unroll
    for (int j=0;j<8;j++){
      s1 += st0[640 + n2*64 + ri*8 + j]*rxL2[j];
      s2 += st0[640 + n2*64 + j*8 + ri]*lxL2[j];
    }
    gtL2[cc]=s1; gbL2[cc]=s2;
  }
  { float s1=0.f, s2=0.f;
    #pragma unroll
    for (int j=0;j<8;j++){
      s1 += st0[768 + g*8 + j]*rxL3[j];
      s2 += st0[768 + j*8 + g]*lxL3[j];
    }
    gtL3=s1; gbL3=s2; }

  const int smax = w*8 + 8;
  for (int s=0; s<smax; s++){
    const float* ks_ = &kS[s*64 + g*8];
    const float* vs_ = &vS[s*64 + g*8];
    const float* uL_ = &uvS[s*176];
    const float* vR_ = &uvS[s*176 + 88];
    float dv0 = vs_[0]*qr[0]+vs_[1]*qr[1]+vs_[2]*qr[2]+vs_[3]*qr[3];
    float dv1 = vs_[4]*qr[4]+vs_[5]*qr[5]+vs_[6]*qr[6]+vs_[7]*qr[7];
    float dn = 0.f;
    #pragma unroll
    for (int cc=0;cc<8;cc++) dn += ks_[cc]*qr[cc];
    float d1L0=0.f,d2L0=0.f;
    #pragma unroll
    for (int j=0;j<4;j++){ d1L0 += vR_[4*g+j]*rxL0[j]; d2L0 += uL_[4*g+j]*lxL0[j]; }
    float d1L1=0.f,d2L1=0.f;
    #pragma unroll
    for (int j=0;j<8;j++){ d1L1 += vR_[32+n1*8+j]*rxL1[j]; d2L1 += uL_[32+n1*8+j]*lxL1[j]; }
    float d1L2=0.f,d2L2=0.f;
    #pragma unroll
    for (int j=0;j<8;j++){ d1L2 += vR_[64+n2*8+j]*rxL2[j]; d2L2 += uL_[64+n2*8+j]*lxL2[j]; }
    float d1L3=0.f,d2L3=0.f;
    #pragma unroll
    for (int j=0;j<8;j++){ d1L3 += vR_[80+j]*rxL3[j]; d2L3 += uL_[80+j]*lxL3[j]; }
    if (s<=t){
      den += dn;
      #pragma unroll
      for (int cc=0;cc<8;cc++) yacc[cc] += ks_[cc]*((cc<4)?dv0:dv1);
      #pragma unroll
      for (int cc=0;cc<4;cc++){
        gtL0[cc] += uL_[4*g+cc]*d1L0;          gbL0[cc] += vR_[4*g+cc]*d2L0;
        gtL1[cc] += uL_[32+n1*8+ri1+cc]*d1L1;  gbL1[cc] += vR_[32+n1*8+ri1+cc]*d2L1;
      }
      #pragma unroll
      for (int cc=0;cc<2;cc++){
        gtL2[cc] += uL_[64+n2*8+ri2+cc]*d1L2;  gbL2[cc] += vR_[64+n2*8+ri2+cc]*d2L2;
      }
      gtL3 += uL_[80+g]*d1L3;  gbL3 += vR_[80+g]*d2L3;
    }
  }
  __syncthreads();

  { float* gr = &uvS[t*176];
    #pragma unroll
    for (int cc=0;cc<4;cc++){
      gr[4*g+cc] = gtL0[cc];                 gr[88+4*g+cc] = gbL0[cc];
      gr[32+n1*8+ri1+cc] = gtL1[cc];         gr[88+32+n1*8+ri1+cc] = gbL1[cc];
    }
    #pragma unroll
    for (int cc=0;cc<2;cc++){
      gr[64+n2*8+ri2+cc] = gtL2[cc];         gr[88+64+n2*8+ri2+cc] = gbL2[cc];
    }
    gr[80+g] = gtL3;  gr[88+80+g] = gbL3;
  }
  __syncthreads();

  den += __shfl_xor(den,1); den += __shfl_xor(den,2); den += __shfl_xor(den,4);
  float inv = 1.f / fmaxf(den, 1e-6f);
  const float* gr = &uvS[t*176];
  float yout[8];
  #pragma unroll
  for (int cc=0;cc<8;cc++){
    int j = g*8 + cc;
    float y = yacc[cc];
    if (cc<4){
      #pragma unroll
      for (int rr=0;rr<4;rr++) y += ULs[cc*4+rr]*gr[g*4+rr];
    } else {
      #pragma unroll
      for (int rr=0;rr<4;rr++) y += URs[(cc-4)*4+rr]*gr[88+g*4+rr];
    }
    { int seg=j>>4, pos=j&15;
      if (pos<8){
        #pragma unroll
        for (int rr=0;rr<8;rr++) y += ULs[16+pos*8+rr]*gr[32+seg*8+rr];
      } else {
        #pragma unroll
        for (int rr=0;rr<8;rr++) y += URs[16+(pos-8)*8+rr]*gr[88+32+seg*8+rr];
      } }
    { int seg=j>>5, pos=j&31;
      if (pos<16){
        #pragma unroll
        for (int rr=0;rr<8;rr++) y += ULs[80+pos*8+rr]*gr[64+seg*8+rr];
      } else {
        #pragma unroll
        for (int rr=0;rr<8;rr++) y += URs[80+(pos-16)*8+rr]*gr[88+64+seg*8+rr];
      } }
    { int pos=j;
      if (pos<32){
        #pragma unroll
        for (int rr=0;rr<8;rr++) y += ULs[208+pos*8+rr]*gr[80+rr];
      } else {
        #pragma unroll
        for (int rr=0;rr<8;rr++) y += URs[208+(pos-32)*8+rr]*gr[88+80+rr];
      } }
    yout[cc] = y*inv;
  }
  u16* yp = Yb + row*64 + g*8;
  ushort4 o1, o2;
  o1.x=f2b(yout[0]); o1.y=f2b(yout[1]); o1.z=f2b(yout[2]); o1.w=f2b(yout[3]);
  o2.x=f2b(yout[4]); o2.y=f2b(yout[5]); o2.z=f2b(yout[6]); o2.w=f2b(yout[7]);
  *(ushort4*)yp = o1;
  *(ushort4*)(yp+4) = o2;
}

// ---------------- Kernel 6: output projection — no LDS, no barriers ----------------
__global__ __launch_bounds__(64) void k_outproj2(
    const u16* __restrict__ Yb, const u16* __restrict__ WoF, void* __restrict__ outv,
    const int* __restrict__ fl)
{
  const int f32 = fl[0];
  const int rows0 = blockIdx.x*32;
  const int nt0 = blockIdx.y*16;
  const int lane = threadIdx.x;
  const int quad = lane>>4, l16 = lane&15;

  f32x4 acc[32];
  #pragma unroll
  for (int i=0;i<32;i++) acc[i] = (f32x4){0.f,0.f,0.f,0.f};

  #pragma unroll
  for (int ks=0;ks<2;ks++){
    int ko = ks*32 + quad*8;
    bf16x8 a0 = *(const bf16x8*)(Yb + (size_t)(rows0 + l16)*DH_ + ko);
    bf16x8 a1 = *(const bf16x8*)(Yb + (size_t)(rows0 + 16 + l16)*DH_ + ko);
    #pragma unroll
    for (int nt=0;nt<16;nt++){
      bf16x8 b = *(const bf16x8*)(WoF + ((size_t)(ks*64 + nt0 + nt)*64 + lane)*8);
      acc[nt]    = __builtin_amdgcn_mfma_f32_16x16x32_bf16(a0,b,acc[nt],0,0,0);
      acc[16+nt] = __builtin_amdgcn_mfma_f32_16x16x32_bf16(a1,b,acc[16+nt],0,0,0);
    }
  }
  #pragma unroll
  for (int sp=0;sp<2;sp++){
    #pragma unroll
    for (int nt=0;nt<16;nt++){
      #pragma unroll
      for (int i=0;i<4;i++){
        int row = rows0 + sp*16 + quad*4 + i;
        int col = (nt0+nt)*16 + l16;
        size_t idx = (size_t)row*DM_ + col;
        float v = acc[sp*16+nt][i];
        if (f32) ((float*)outv)[idx] = v;
        else ((u16*)outv)[idx] = f2b(v);
      }
    }
  }
}

extern "C" void kernel_launch(void* const* d_in, const int* in_sizes, int n_in,
                              void* d_out, int out_size, void* d_ws, size_t ws_size,
                              hipStream_t stream) {
  const void* x  = d_in[0];
  const void* Wq = d_in[1];
  const void* Wk = d_in[2];
  const void* Wv = d_in[3];
  const void* Wo = d_in[4];
  const void* UL[4] = {d_in[5],d_in[6],d_in[7],d_in[8]};
  const void* VR[4] = {d_in[9],d_in[10],d_in[11],d_in[12]};
  const void* UR[4] = {d_in[13],d_in[14],d_in[15],d_in[16]};
  const void* VL[4] = {d_in[17],d_in[18],d_in[19],d_in[20]};

  int* flag = (int*)d_ws;
  float* ws = (float*)d_ws + 16;
  float* q    = ws;
  float* kf   = q    + (size_t)BT_*64;
  float* vf   = kf   + (size_t)BT_*64;
  float* uLa  = vf   + (size_t)BT_*64;
  float* vRa  = uLa  + (size_t)BT_*88;
  float* vrxa = vRa  + (size_t)BT_*88;
  float* vlxa = vrxa + (size_t)BT_*88;
  float* SL   = vlxa + (size_t)BT_*88;
  float* SP   = SL   + (size_t)B_*NCH_*STATE_;
  u16*   Yb   = (u16*)(SP + (size_t)B_*NCH_*STATE_);
  u16*   WF   = Yb  + (size_t)BT_*64;
  u16*   WoF  = WF  + (size_t)196608;
  u16*   PF   = WoF + (size_t)65536;
  u16*   qb16 = PF  + (size_t)18432;
  u16*   kb16 = qb16 + (size_t)BT_*64;
  u16*   vb16 = kb16 + (size_t)BT_*64;

  k_detect<<<1, 64, 0, stream>>>((const u16*)x, flag);
  k_wfrag<<<137, 256, 0, stream>>>(Wq, Wk, Wv, Wo,
      UL[0],UL[1],UL[2],UL[3], VR[0],VR[1],VR[2],VR[3], VL[0],VL[1],VL[2],VL[3],
      WF, WoF, PF, flag);
  k_proj2<<<512, 64, 0, stream>>>(x, WF, q, kf, vf, qb16, kb16, vb16, flag);
  k_prep2<<<BT_/16, 64, 0, stream>>>(qb16, kb16, vb16, PF, uLa, vRa, vrxa, vlxa);
  k_chunksum<<<B_*NCH_, 256, 0, stream>>>(kf, vf, uLa, vRa, SL);
  k_prefix<<<B_, 256, 0, stream>>>(SL, SP);
  k_intra<<<B_*NCH_, 256, 0, stream>>>(q, kf, vf, uLa, vRa, vrxa, vlxa, SP,
      UL[0],UL[1],UL[2],UL[3], UR[0],UR[1],UR[2],UR[3], Yb, flag);
  k_outproj2<<<dim3(512, 4), 64, 0, stream>>>(Yb, WoF, d_out, flag);
}